// Round 1
// baseline (3616.384 us; speedup 1.0000x reference)
//
#include <hip/hip_runtime.h>
#include <hip/hip_bf16.h>

#define N_ 2
#define P_ 100
#define C_ 256
#define H_ 128
#define W_ 192
#define HW_ 24576
#define KK_ 9
#define E_ 2304
#define NH_ 8
#define DH_ 288
#define FFN_ 2048
#define NP_ 200
#define ROWS_ 1800   // NP_*KK_

__device__ __forceinline__ float bf2f(unsigned short u){
  return __uint_as_float(((unsigned)u) << 16);
}

// ---------------- softmax over P axis of mask_preds ----------------
__global__ __launch_bounds__(256) void k_softmax(const float* __restrict__ mp, float* __restrict__ sig){
  int idx = blockIdx.x*256 + threadIdx.x;
  if(idx >= N_*HW_) return;
  int n = idx / HW_, hw = idx - n*HW_;
  const float* base = mp + (size_t)n*P_*HW_ + hw;
  float m = -1e30f;
  for(int p=0;p<P_;p++) m = fmaxf(m, base[(size_t)p*HW_]);
  float s = 0.f;
  for(int p=0;p<P_;p++) s += __expf(base[(size_t)p*HW_] - m);
  float inv = 1.f/s;
  float* ob = sig + (size_t)n*P_*HW_ + hw;
  for(int p=0;p<P_;p++) ob[(size_t)p*HW_] = __expf(base[(size_t)p*HW_] - m)*inv;
}

// ---------------- pf permute: pf[np][kk][c] = prop[n][p][c*9+kk] ----------------
__global__ __launch_bounds__(256) void k_permute_pf(const float* __restrict__ prop, float* __restrict__ pf){
  int i = blockIdx.x*256 + threadIdx.x;
  if(i >= ROWS_*C_) return;
  int c = i & 255;
  int r = i >> 8;            // np*9+kk
  int kk = r % 9, np = r / 9;
  pf[i] = prop[(size_t)np*E_ + c*KK_ + kk];
}

// ---------------- x_feat stage 1: split-K partials ----------------
// block: (kb<96, cb<8, n<2). hw chunk = 256 (2 sub-chunks of 128). c tile = 32.
__global__ __launch_bounds__(256) void k_xfeat1(const float* __restrict__ sig, const float* __restrict__ x,
                                                float* __restrict__ partial){
  int kb = blockIdx.x, cb = blockIdx.y, n = blockIdx.z;
  int tid = threadIdx.x;
  int c4 = tid & 7, pg = tid >> 3;
  __shared__ float sg[100][129];
  __shared__ __hip_bfloat16 xsb[128][36];
  float acc[4][4] = {};
  int hw0 = kb*256;
  for(int sc=0; sc<2; sc++){
    int hwb = hw0 + sc*128;
    for(int i=tid; i<100*128; i+=256){
      int p = i >> 7, k = i & 127;
      sg[p][k] = sig[((size_t)n*P_ + p)*HW_ + hwb + k];
    }
    for(int i=tid; i<32*128; i+=256){
      int cl = i >> 7, k = i & 127;
      xsb[k][cl] = __float2bfloat16(x[((size_t)n*C_ + cb*32 + cl)*HW_ + hwb + k]);
    }
    __syncthreads();
    #pragma unroll 4
    for(int k=0;k<128;k++){
      short4 raw = *(const short4*)&xsb[k][c4*4];
      float x0 = bf2f((unsigned short)raw.x);
      float x1 = bf2f((unsigned short)raw.y);
      float x2 = bf2f((unsigned short)raw.z);
      float x3 = bf2f((unsigned short)raw.w);
      #pragma unroll
      for(int j=0;j<4;j++){
        int p = pg + 32*j;
        if(p < P_){
          float sv = sg[p][k];
          acc[j][0] += sv*x0; acc[j][1] += sv*x1; acc[j][2] += sv*x2; acc[j][3] += sv*x3;
        }
      }
    }
    __syncthreads();
  }
  #pragma unroll
  for(int j=0;j<4;j++){
    int p = pg + 32*j;
    if(p < P_){
      float4 v = {acc[j][0],acc[j][1],acc[j][2],acc[j][3]};
      *(float4*)&partial[(((size_t)n*96 + kb)*P_ + p)*C_ + cb*32 + c4*4] = v;
    }
  }
}

// ---------------- x_feat stage 2: reduce over 96 chunks ----------------
__global__ __launch_bounds__(256) void k_xfeat2(const float* __restrict__ partial, float* __restrict__ xfeat){
  int np = blockIdx.x;
  int n = np / P_, p = np - n*P_;
  int c = threadIdx.x;
  float s = 0.f;
  for(int kb=0;kb<96;kb++) s += partial[(((size_t)n*96 + kb)*P_ + p)*C_ + c];
  xfeat[(size_t)np*C_ + c] = s;
}

// ---------------- generic tiled fp32 GEMM: out = act(A @ W^T + bias) ----------------
// BM=BN=64, BK=32, 256 threads, 4x4 micro-tile. act: 0 none, 1 relu.
__global__ __launch_bounds__(256) void k_gemm(const float* __restrict__ A, const float* __restrict__ Wt,
    const float* __restrict__ bias, float* __restrict__ out, int M, int N, int K, int act)
{
  __shared__ float As[32][68];
  __shared__ float Bs[32][68];
  const int m0 = blockIdx.y*64, n0 = blockIdx.x*64;
  const int tid = threadIdx.x;
  const int tx = tid & 15, ty = tid >> 4;
  float acc[4][4] = {};
  for(int k0=0;k0<K;k0+=32){
    #pragma unroll
    for(int i=0;i<8;i++){
      int idx = tid + i*256;
      int r = idx >> 5, kk = idx & 31;
      int m = m0 + r;
      As[kk][r] = (m < M) ? A[(size_t)m*K + k0 + kk] : 0.f;
      Bs[kk][r] = Wt[(size_t)(n0 + r)*K + k0 + kk];
    }
    __syncthreads();
    #pragma unroll
    for(int k=0;k<32;k++){
      const float4 a = *(const float4*)&As[k][ty*4];
      const float4 b = *(const float4*)&Bs[k][tx*4];
      float av[4] = {a.x,a.y,a.z,a.w};
      float bv[4] = {b.x,b.y,b.z,b.w};
      #pragma unroll
      for(int i=0;i<4;i++)
        #pragma unroll
        for(int j=0;j<4;j++) acc[i][j] += av[i]*bv[j];
    }
    __syncthreads();
  }
  #pragma unroll
  for(int i=0;i<4;i++){
    int m = m0 + ty*4 + i;
    if(m < M){
      float v[4];
      #pragma unroll
      for(int j=0;j<4;j++){
        float t = acc[i][j];
        if(bias) t += bias[n0 + tx*4 + j];
        if(act == 1) t = fmaxf(t, 0.f);
        v[j] = t;
      }
      float4 o = {v[0],v[1],v[2],v[3]};
      *(float4*)&out[(size_t)m*N + n0 + tx*4] = o;
    }
  }
}

// ---------------- GEMM (N=256) + bias + residual + LayerNorm + act ----------------
// BM=32, BN=256, BK=32. act: 0 none, 1 relu, 2 sigmoid. thread cols: tx*4 and 128+tx*4.
__global__ __launch_bounds__(256) void k_gemm_ln(const float* __restrict__ A, const float* __restrict__ Wt,
    const float* __restrict__ bias, const float* __restrict__ res,
    const float* __restrict__ g, const float* __restrict__ b,
    float* __restrict__ out, int M, int K, int act)
{
  __shared__ float As[32][36];
  __shared__ float Bs[32][260];
  const int m0 = blockIdx.x*32;
  const int tid = threadIdx.x;
  const int tx = tid & 31, ty = tid >> 5;
  float acc[4][8] = {};
  for(int k0=0;k0<K;k0+=32){
    #pragma unroll
    for(int i=0;i<4;i++){
      int idx = tid + i*256;
      int r = idx >> 5, kk = idx & 31;
      int m = m0 + r;
      As[kk][r] = (m < M) ? A[(size_t)m*K + k0 + kk] : 0.f;
    }
    for(int i=0;i<32;i++){
      int idx = tid + i*256;
      int r = idx >> 5, kk = idx & 31;
      Bs[kk][r] = Wt[(size_t)r*K + k0 + kk];
    }
    __syncthreads();
    #pragma unroll
    for(int k=0;k<32;k++){
      const float4 a  = *(const float4*)&As[k][ty*4];
      const float4 b0 = *(const float4*)&Bs[k][tx*4];
      const float4 b1 = *(const float4*)&Bs[k][128 + tx*4];
      float av[4] = {a.x,a.y,a.z,a.w};
      float bv[8] = {b0.x,b0.y,b0.z,b0.w,b1.x,b1.y,b1.z,b1.w};
      #pragma unroll
      for(int i=0;i<4;i++)
        #pragma unroll
        for(int j=0;j<8;j++) acc[i][j] += av[i]*bv[j];
    }
    __syncthreads();
  }
  #pragma unroll
  for(int i=0;i<4;i++){
    int m = m0 + ty*4 + i;
    bool valid = (m < M);
    float v[8]; float s=0.f, q=0.f;
    #pragma unroll
    for(int j=0;j<8;j++){
      int c = (j<4) ? tx*4+j : 128 + tx*4 + (j-4);
      float t = acc[i][j];
      if(bias) t += bias[c];
      if(res && valid) t += res[(size_t)m*C_ + c];
      v[j] = t; s += t; q += t*t;
    }
    #pragma unroll
    for(int off=16; off; off>>=1){ s += __shfl_xor(s, off, 32); q += __shfl_xor(q, off, 32); }
    float mean = s*(1.f/256.f);
    float rstd = rsqrtf(q*(1.f/256.f) - mean*mean + 1e-5f);
    if(valid){
      float o[8];
      #pragma unroll
      for(int j=0;j<8;j++){
        int c = (j<4) ? tx*4+j : 128 + tx*4 + (j-4);
        float t = (v[j]-mean)*rstd*g[c] + b[c];
        if(act==1) t = fmaxf(t, 0.f);
        else if(act==2) t = 1.f/(1.f + __expf(-t));
        o[j] = t;
      }
      float4 o0 = {o[0],o[1],o[2],o[3]}, o1 = {o[4],o[5],o[6],o[7]};
      *(float4*)&out[(size_t)m*C_ + tx*4] = o0;
      *(float4*)&out[(size_t)m*C_ + 128 + tx*4] = o1;
    }
  }
}

// ---------------- gate = i_in * p_in ----------------
__global__ __launch_bounds__(256) void k_gate(const float* __restrict__ inp, const float* __restrict__ params,
                                              float* __restrict__ gate){
  int i = blockIdx.x*256 + threadIdx.x;
  if(i >= ROWS_*C_) return;
  int c = i & 255, r = i >> 8;
  int np = r / 9;
  gate[i] = inp[(size_t)r*512 + c] * params[(size_t)np*512 + c];
}

// ---------------- block LN helper (256 threads, 1 val each) ----------------
__device__ __forceinline__ void block_stats(float v, float* red, int slot, float& mean, float& rstd){
  float s = v, q = v*v;
  #pragma unroll
  for(int off=32; off; off>>=1){ s += __shfl_xor(s, off, 64); q += __shfl_xor(q, off, 64); }
  int wid = threadIdx.x >> 6;
  if((threadIdx.x & 63) == 0){ red[slot + wid] = s; red[slot + 4 + wid] = q; }
  __syncthreads();
  s = red[slot+0]+red[slot+1]+red[slot+2]+red[slot+3];
  q = red[slot+4]+red[slot+5]+red[slot+6]+red[slot+7];
  mean = s*(1.f/256.f);
  rstd = rsqrtf(q*(1.f/256.f) - mean*mean + 1e-5f);
}

// ---------------- feat = ug * LN(p_out) + ig * LN(i_out) ----------------
__global__ __launch_bounds__(256) void k_combine(const float* __restrict__ params, const float* __restrict__ inp,
  const float* __restrict__ ug, const float* __restrict__ ig,
  const float* __restrict__ nout_g, const float* __restrict__ nout_b,
  const float* __restrict__ inout_g, const float* __restrict__ inout_b,
  float* __restrict__ feat)
{
  __shared__ float red[16];
  int r = blockIdx.x;           // np*9+kk
  int np = r / 9;
  int c = threadIdx.x;
  float pv = params[(size_t)np*512 + 256 + c];
  float mean, rstd;
  block_stats(pv, red, 0, mean, rstd);
  float pn = (pv - mean)*rstd*nout_g[c] + nout_b[c];
  float iv = inp[(size_t)r*512 + 256 + c];
  float mean2, rstd2;
  block_stats(iv, red, 8, mean2, rstd2);
  float iw = (iv - mean2)*rstd2*inout_g[c] + inout_b[c];
  size_t o = (size_t)r*C_ + c;
  feat[o] = ug[o]*pn + ig[o]*iw;
}

// ---------------- attention: one block per (head, n) ----------------
__global__ __launch_bounds__(256) void k_attn(const float* __restrict__ qkv, float* __restrict__ attnO){
  __shared__ float S[100][104];
  const int head = blockIdx.x, n = blockIdx.y;
  const float scale = 0.05892556509887896f;   // 1/sqrt(288)
  const size_t qbase = (size_t)n*P_*6912 + head*DH_;
  for(int i=threadIdx.x; i<P_*P_; i+=256){
    int qp = i/P_, kp = i - qp*P_;
    const float* qptr = qkv + qbase + (size_t)qp*6912;
    const float* kptr = qkv + qbase + (size_t)kp*6912 + E_;
    float s = 0.f;
    #pragma unroll 4
    for(int d=0; d<DH_; d+=4){
      float4 a = *(const float4*)(qptr+d);
      float4 c = *(const float4*)(kptr+d);
      s += a.x*c.x + a.y*c.y + a.z*c.z + a.w*c.w;
    }
    S[qp][kp] = s*scale;
  }
  __syncthreads();
  if(threadIdx.x < P_){
    float* row = S[threadIdx.x];
    float m = -1e30f;
    for(int k=0;k<P_;k++) m = fmaxf(m, row[k]);
    float s = 0.f;
    for(int k=0;k<P_;k++){ float e = __expf(row[k]-m); row[k]=e; s+=e; }
    float inv = 1.f/s;
    for(int k=0;k<P_;k++) row[k] *= inv;
  }
  __syncthreads();
  for(int i=threadIdx.x; i<P_*DH_; i+=256){
    int qp = i/DH_, d = i - qp*DH_;
    const float* vb = qkv + qbase + 2*E_ + d;
    float s = 0.f;
    for(int kp=0;kp<P_;kp++) s += S[qp][kp]*vb[(size_t)kp*6912];
    attnO[(size_t)(n*P_+qp)*E_ + head*DH_ + d] = s;
  }
}

// ---------------- obj1 = LN(obj0 + tproj) over E=2304 ----------------
__global__ __launch_bounds__(256) void k_add_ln2304(const float* __restrict__ obj0, const float* __restrict__ tp,
  const float* __restrict__ g, const float* __restrict__ b, float* __restrict__ out)
{
  __shared__ float red[8];
  int row = blockIdx.x;
  float v[9]; float s=0.f, q=0.f;
  #pragma unroll
  for(int j=0;j<9;j++){
    int e = threadIdx.x + j*256;
    float t = obj0[(size_t)row*E_ + e] + tp[(size_t)row*E_ + e];
    v[j]=t; s+=t; q+=t*t;
  }
  #pragma unroll
  for(int off=32; off; off>>=1){ s += __shfl_xor(s, off, 64); q += __shfl_xor(q, off, 64); }
  int wid = threadIdx.x>>6;
  if((threadIdx.x&63)==0){ red[wid]=s; red[4+wid]=q; }
  __syncthreads();
  s = red[0]+red[1]+red[2]+red[3]; q = red[4]+red[5]+red[6]+red[7];
  float mean = s*(1.f/2304.f);
  float rstd = rsqrtf(q*(1.f/2304.f) - mean*mean + 1e-5f);
  #pragma unroll
  for(int j=0;j<9;j++){
    int e = threadIdx.x + j*256;
    out[(size_t)row*E_ + e] = (v[j]-mean)*rstd*g[e] + b[e];
  }
}

// ---------------- obj_kernels output transpose ----------------
__global__ __launch_bounds__(256) void k_objk(const float* __restrict__ obj2, float* __restrict__ outk){
  int i = blockIdx.x*256 + threadIdx.x;
  if(i >= ROWS_*C_) return;
  int kk = i % 9; int t = i / 9; int c = t & 255; int np = t >> 8;
  outk[i] = obj2[((size_t)np*9 + kk)*C_ + c];
}

// ---------------- dynamic conv: out[n,p,h,w] = sum_{c,ky,kx} ker[np][ky*3+kx][c]*x[n,c,h+ky-1,w+kx-1]
// block: (wt<3, ht<16, n*7+pt). thread: wg=tid&7 (8 w of 8), pg=(tid>>3)&3 (4 p of 4), hi=tid>>5 (8 h)
__global__ __launch_bounds__(256) void k_conv(const float* __restrict__ x, const float* __restrict__ ker,
                                              float* __restrict__ out){
  const int wt = blockIdx.x, ht = blockIdx.y, pz = blockIdx.z;
  const int n = pz / 7, pt = pz - n*7;
  const int tid = threadIdx.x;
  const int wg = tid & 7, pg = (tid>>3)&3, hi = tid>>5;
  const int w0 = wt*64, h0 = ht*8;
  __shared__ float xs[8][10][68];
  __shared__ float ks[8][16][12];
  float acc[4][8] = {};
  for(int c0=0; c0<C_; c0+=8){
    for(int i = tid; i < 8*10*66; i += 256){
      int wx = i % 66; int t = i / 66; int hy = t % 10; int ci = t / 10;
      int hh = h0 - 1 + hy, ww = w0 - 1 + wx;
      float v = 0.f;
      if(hh >= 0 && hh < H_ && ww >= 0 && ww < W_)
        v = x[(((size_t)n*C_ + c0+ci)*H_ + hh)*W_ + ww];
      xs[ci][hy][wx] = v;
    }
    for(int i = tid; i < 16*9*8; i += 256){
      int ci = i % 8; int t = i / 8; int tap = t % 9; int pp = t / 9;
      int p = pt*16 + pp;
      float v = 0.f;
      if(p < P_) v = ker[((size_t)(n*P_+p)*9 + tap)*C_ + c0 + ci];
      ks[ci][pp][tap] = v;
    }
    __syncthreads();
    for(int ci=0; ci<8; ci++){
      #pragma unroll
      for(int ky=0; ky<3; ky++){
        float xv[10];
        #pragma unroll
        for(int t=0;t<10;t++) xv[t] = xs[ci][hi+ky][wg*8 + t];
        #pragma unroll
        for(int ii=0; ii<4; ii++){
          int pp = pg*4 + ii;
          float k0 = ks[ci][pp][ky*3+0];
          float k1 = ks[ci][pp][ky*3+1];
          float k2 = ks[ci][pp][ky*3+2];
          #pragma unroll
          for(int j=0;j<8;j++)
            acc[ii][j] += k0*xv[j] + k1*xv[j+1] + k2*xv[j+2];
        }
      }
    }
    __syncthreads();
  }
  int h = h0 + hi;
  #pragma unroll
  for(int ii=0;ii<4;ii++){
    int p = pt*16 + pg*4 + ii;
    if(p < P_){
      float* op = &out[((size_t)(n*P_+p)*H_ + h)*W_ + w0 + wg*8];
      float4 o0 = {acc[ii][0],acc[ii][1],acc[ii][2],acc[ii][3]};
      float4 o1 = {acc[ii][4],acc[ii][5],acc[ii][6],acc[ii][7]};
      *(float4*)op = o0;
      *(float4*)(op+4) = o1;
    }
  }
}

extern "C" void kernel_launch(void* const* d_in, const int* in_sizes, int n_in,
                              void* d_out, int out_size, void* d_ws, size_t ws_size,
                              hipStream_t stream)
{
  (void)in_sizes; (void)n_in; (void)out_size; (void)ws_size;
  const float* x          = (const float*)d_in[0];
  const float* prop       = (const float*)d_in[1];
  const float* mask_pred  = (const float*)d_in[2];
  const float* ku_dyn_w   = (const float*)d_in[3];
  const float* ku_dyn_b   = (const float*)d_in[4];
  const float* ku_in_w    = (const float*)d_in[5];
  const float* ku_in_b    = (const float*)d_in[6];
  const float* ku_ig_w    = (const float*)d_in[7];
  const float* ku_ig_b    = (const float*)d_in[8];
  const float* ku_ug_w    = (const float*)d_in[9];
  const float* ku_ug_b    = (const float*)d_in[10];
  const float* ku_nin_g   = (const float*)d_in[11];
  const float* ku_nin_b   = (const float*)d_in[12];
  const float* ku_nout_g  = (const float*)d_in[13];
  const float* ku_nout_b  = (const float*)d_in[14];
  const float* ku_inin_g  = (const float*)d_in[15];
  const float* ku_inin_b  = (const float*)d_in[16];
  const float* ku_inout_g = (const float*)d_in[17];
  const float* ku_inout_b = (const float*)d_in[18];
  const float* ku_fc_w    = (const float*)d_in[19];
  const float* ku_fc_b    = (const float*)d_in[20];
  const float* ku_fcn_g   = (const float*)d_in[21];
  const float* ku_fcn_b   = (const float*)d_in[22];
  const float* attn_in_w  = (const float*)d_in[23];
  const float* attn_in_b  = (const float*)d_in[24];
  const float* attn_out_w = (const float*)d_in[25];
  const float* attn_out_b = (const float*)d_in[26];
  const float* attn_ln_g  = (const float*)d_in[27];
  const float* attn_ln_b  = (const float*)d_in[28];
  const float* ffn_w1     = (const float*)d_in[29];
  const float* ffn_b1     = (const float*)d_in[30];
  const float* ffn_w2     = (const float*)d_in[31];
  const float* ffn_b2     = (const float*)d_in[32];
  const float* ffn_ln_g   = (const float*)d_in[33];
  const float* ffn_ln_b   = (const float*)d_in[34];
  const float* mask_fc_ws = (const float*)d_in[35];
  const float* mask_fc_ln_g = (const float*)d_in[36];
  const float* mask_fc_ln_b = (const float*)d_in[37];
  const float* fc_mask_w  = (const float*)d_in[38];
  const float* fc_mask_b  = (const float*)d_in[39];

  float* ws = (float*)d_ws;
  // region0 [0, 4.92M): sig, later reused as FFN hidden
  float* sig     = ws;
  float* hbuf    = ws;
  // region1 [4.92M, 9.83M): xfeat partials, later qkv/attnO/tproj
  float* partial = ws + 4915200;
  float* qkv     = ws + 4915200;
  float* attnO   = ws + 4915200 + 1382400;
  float* tproj   = ws + 4915200 + 1843200;
  // region2: persistent smalls
  float* xfeat   = ws + 9830400;
  float* params  = xfeat + 51200;
  float* pf      = params + 102400;
  float* inp     = pf + 460800;
  float* gate    = inp + 921600;
  float* ig      = gate + 460800;
  float* ug      = ig + 460800;
  float* feat    = ug + 460800;
  float* obj0    = feat + 460800;
  float* obj1    = obj0 + 460800;
  float* obj2    = obj1 + 460800;
  float* mf1     = obj2 + 460800;
  float* mf2     = mf1 + 460800;
  float* mfF     = mf2 + 460800;

  float* out_masks = (float*)d_out;
  float* out_kern  = out_masks + (size_t)N_*P_*HW_;

  k_softmax<<<192, 256, 0, stream>>>(mask_pred, sig);
  k_permute_pf<<<1800, 256, 0, stream>>>(prop, pf);
  k_xfeat1<<<dim3(96,8,2), 256, 0, stream>>>(sig, x, partial);
  k_xfeat2<<<200, 256, 0, stream>>>(partial, xfeat);
  k_gemm<<<dim3(8,4),  256, 0, stream>>>(xfeat, ku_dyn_w, ku_dyn_b, params, 200, 512, 256, 0);
  k_gemm<<<dim3(8,29), 256, 0, stream>>>(pf, ku_in_w, ku_in_b, inp, 1800, 512, 256, 0);
  k_gate<<<1800, 256, 0, stream>>>(inp, params, gate);
  k_gemm_ln<<<57, 256, 0, stream>>>(gate, ku_ig_w, ku_ig_b, nullptr, ku_inin_g, ku_inin_b, ig, 1800, 256, 2);
  k_gemm_ln<<<57, 256, 0, stream>>>(gate, ku_ug_w, ku_ug_b, nullptr, ku_nin_g, ku_nin_b, ug, 1800, 256, 2);
  k_combine<<<1800, 256, 0, stream>>>(params, inp, ug, ig, ku_nout_g, ku_nout_b, ku_inout_g, ku_inout_b, feat);
  k_gemm_ln<<<57, 256, 0, stream>>>(feat, ku_fc_w, ku_fc_b, nullptr, ku_fcn_g, ku_fcn_b, obj0, 1800, 256, 1);
  k_gemm<<<dim3(108,4), 256, 0, stream>>>(obj0, attn_in_w, attn_in_b, qkv, 200, 6912, 2304, 0);
  k_attn<<<dim3(8,2), 256, 0, stream>>>(qkv, attnO);
  k_gemm<<<dim3(36,4), 256, 0, stream>>>(attnO, attn_out_w, attn_out_b, tproj, 200, 2304, 2304, 0);
  k_add_ln2304<<<200, 256, 0, stream>>>(obj0, tproj, attn_ln_g, attn_ln_b, obj1);
  k_gemm<<<dim3(32,29), 256, 0, stream>>>(obj1, ffn_w1, ffn_b1, hbuf, 1800, 2048, 256, 1);
  k_gemm_ln<<<57, 256, 0, stream>>>(hbuf, ffn_w2, ffn_b2, obj1, ffn_ln_g, ffn_ln_b, obj2, 1800, 2048, 0);
  k_gemm_ln<<<57, 256, 0, stream>>>(obj2, mask_fc_ws,          nullptr, nullptr, mask_fc_ln_g,       mask_fc_ln_b,       mf1, 1800, 256, 1);
  k_gemm_ln<<<57, 256, 0, stream>>>(mf1,  mask_fc_ws + 65536,  nullptr, nullptr, mask_fc_ln_g + 256, mask_fc_ln_b + 256, mf2, 1800, 256, 1);
  k_gemm_ln<<<57, 256, 0, stream>>>(mf2,  mask_fc_ws + 131072, nullptr, nullptr, mask_fc_ln_g + 512, mask_fc_ln_b + 512, mf1, 1800, 256, 1);
  k_gemm<<<dim3(4,29), 256, 0, stream>>>(mf1, fc_mask_w, fc_mask_b, mfF, 1800, 256, 256, 0);
  k_objk<<<1800, 256, 0, stream>>>(obj2, out_kern);
  k_conv<<<dim3(3,16,14), 256, 0, stream>>>(x, mfF, out_masks);
}

// Round 2
// 2597.540 us; speedup vs baseline: 1.3922x; 1.3922x over previous
//
#include <hip/hip_runtime.h>
#include <hip/hip_bf16.h>

#define N_ 2
#define P_ 100
#define C_ 256
#define H_ 128
#define W_ 192
#define HW_ 24576
#define KK_ 9
#define E_ 2304
#define NH_ 8
#define DH_ 288
#define FFN_ 2048
#define NP_ 200
#define ROWS_ 1800   // NP_*KK_

__device__ __forceinline__ float bf2f(unsigned short u){
  return __uint_as_float(((unsigned)u) << 16);
}

// ---------------- softmax over P axis of mask_preds ----------------
__global__ __launch_bounds__(256) void k_softmax(const float* __restrict__ mp, float* __restrict__ sig){
  int idx = blockIdx.x*256 + threadIdx.x;
  if(idx >= N_*HW_) return;
  int n = idx / HW_, hw = idx - n*HW_;
  const float* base = mp + (size_t)n*P_*HW_ + hw;
  float m = -1e30f;
  for(int p=0;p<P_;p++) m = fmaxf(m, base[(size_t)p*HW_]);
  float s = 0.f;
  for(int p=0;p<P_;p++) s += __expf(base[(size_t)p*HW_] - m);
  float inv = 1.f/s;
  float* ob = sig + (size_t)n*P_*HW_ + hw;
  for(int p=0;p<P_;p++) ob[(size_t)p*HW_] = __expf(base[(size_t)p*HW_] - m)*inv;
}

// ---------------- pf permute: pf[np][kk][c] = prop[n][p][c*9+kk] ----------------
__global__ __launch_bounds__(256) void k_permute_pf(const float* __restrict__ prop, float* __restrict__ pf){
  int i = blockIdx.x*256 + threadIdx.x;
  if(i >= ROWS_*C_) return;
  int c = i & 255;
  int r = i >> 8;            // np*9+kk
  int kk = r % 9, np = r / 9;
  pf[i] = prop[(size_t)np*E_ + c*KK_ + kk];
}

// ---------------- x_feat stage 1: split-K partials ----------------
__global__ __launch_bounds__(256) void k_xfeat1(const float* __restrict__ sig, const float* __restrict__ x,
                                                float* __restrict__ partial){
  int kb = blockIdx.x, cb = blockIdx.y, n = blockIdx.z;
  int tid = threadIdx.x;
  int c4 = tid & 7, pg = tid >> 3;
  __shared__ float sg[100][129];
  __shared__ __hip_bfloat16 xsb[128][36];
  float acc[4][4] = {};
  int hw0 = kb*256;
  for(int sc=0; sc<2; sc++){
    int hwb = hw0 + sc*128;
    for(int i=tid; i<100*128; i+=256){
      int p = i >> 7, k = i & 127;
      sg[p][k] = sig[((size_t)n*P_ + p)*HW_ + hwb + k];
    }
    for(int i=tid; i<32*128; i+=256){
      int cl = i >> 7, k = i & 127;
      xsb[k][cl] = __float2bfloat16(x[((size_t)n*C_ + cb*32 + cl)*HW_ + hwb + k]);
    }
    __syncthreads();
    #pragma unroll 4
    for(int k=0;k<128;k++){
      short4 raw = *(const short4*)&xsb[k][c4*4];
      float x0 = bf2f((unsigned short)raw.x);
      float x1 = bf2f((unsigned short)raw.y);
      float x2 = bf2f((unsigned short)raw.z);
      float x3 = bf2f((unsigned short)raw.w);
      #pragma unroll
      for(int j=0;j<4;j++){
        int p = pg + 32*j;
        if(p < P_){
          float sv = sg[p][k];
          acc[j][0] += sv*x0; acc[j][1] += sv*x1; acc[j][2] += sv*x2; acc[j][3] += sv*x3;
        }
      }
    }
    __syncthreads();
  }
  #pragma unroll
  for(int j=0;j<4;j++){
    int p = pg + 32*j;
    if(p < P_){
      float4 v = {acc[j][0],acc[j][1],acc[j][2],acc[j][3]};
      *(float4*)&partial[(((size_t)n*96 + kb)*P_ + p)*C_ + cb*32 + c4*4] = v;
    }
  }
}

// ---------------- x_feat stage 2: reduce over 96 chunks ----------------
__global__ __launch_bounds__(256) void k_xfeat2(const float* __restrict__ partial, float* __restrict__ xfeat){
  int np = blockIdx.x;
  int n = np / P_, p = np - n*P_;
  int c = threadIdx.x;
  float s = 0.f;
  for(int kb=0;kb<96;kb++) s += partial[(((size_t)n*96 + kb)*P_ + p)*C_ + c];
  xfeat[(size_t)np*C_ + c] = s;
}

// ---------------- generic tiled fp32 GEMM: out = act(A @ W^T + bias) ----------------
__global__ __launch_bounds__(256) void k_gemm(const float* __restrict__ A, const float* __restrict__ Wt,
    const float* __restrict__ bias, float* __restrict__ out, int M, int N, int K, int act)
{
  __shared__ float As[32][68];
  __shared__ float Bs[32][68];
  const int m0 = blockIdx.y*64, n0 = blockIdx.x*64;
  const int tid = threadIdx.x;
  const int tx = tid & 15, ty = tid >> 4;
  float acc[4][4] = {};
  for(int k0=0;k0<K;k0+=32){
    #pragma unroll
    for(int i=0;i<8;i++){
      int idx = tid + i*256;
      int r = idx >> 5, kk = idx & 31;
      int m = m0 + r;
      As[kk][r] = (m < M) ? A[(size_t)m*K + k0 + kk] : 0.f;
      Bs[kk][r] = Wt[(size_t)(n0 + r)*K + k0 + kk];
    }
    __syncthreads();
    #pragma unroll
    for(int k=0;k<32;k++){
      const float4 a = *(const float4*)&As[k][ty*4];
      const float4 b = *(const float4*)&Bs[k][tx*4];
      float av[4] = {a.x,a.y,a.z,a.w};
      float bv[4] = {b.x,b.y,b.z,b.w};
      #pragma unroll
      for(int i=0;i<4;i++)
        #pragma unroll
        for(int j=0;j<4;j++) acc[i][j] += av[i]*bv[j];
    }
    __syncthreads();
  }
  #pragma unroll
  for(int i=0;i<4;i++){
    int m = m0 + ty*4 + i;
    if(m < M){
      float v[4];
      #pragma unroll
      for(int j=0;j<4;j++){
        float t = acc[i][j];
        if(bias) t += bias[n0 + tx*4 + j];
        if(act == 1) t = fmaxf(t, 0.f);
        v[j] = t;
      }
      float4 o = {v[0],v[1],v[2],v[3]};
      *(float4*)&out[(size_t)m*N + n0 + tx*4] = o;
    }
  }
}

// ---------------- GEMM (N=256) + bias + residual + LayerNorm + act ----------------
__global__ __launch_bounds__(256) void k_gemm_ln(const float* __restrict__ A, const float* __restrict__ Wt,
    const float* __restrict__ bias, const float* __restrict__ res,
    const float* __restrict__ g, const float* __restrict__ b,
    float* __restrict__ out, int M, int K, int act)
{
  __shared__ float As[32][36];
  __shared__ float Bs[32][260];
  const int m0 = blockIdx.x*32;
  const int tid = threadIdx.x;
  const int tx = tid & 31, ty = tid >> 5;
  float acc[4][8] = {};
  for(int k0=0;k0<K;k0+=32){
    #pragma unroll
    for(int i=0;i<4;i++){
      int idx = tid + i*256;
      int r = idx >> 5, kk = idx & 31;
      int m = m0 + r;
      As[kk][r] = (m < M) ? A[(size_t)m*K + k0 + kk] : 0.f;
    }
    for(int i=0;i<32;i++){
      int idx = tid + i*256;
      int r = idx >> 5, kk = idx & 31;
      Bs[kk][r] = Wt[(size_t)r*K + k0 + kk];
    }
    __syncthreads();
    #pragma unroll
    for(int k=0;k<32;k++){
      const float4 a  = *(const float4*)&As[k][ty*4];
      const float4 b0 = *(const float4*)&Bs[k][tx*4];
      const float4 b1 = *(const float4*)&Bs[k][128 + tx*4];
      float av[4] = {a.x,a.y,a.z,a.w};
      float bv[8] = {b0.x,b0.y,b0.z,b0.w,b1.x,b1.y,b1.z,b1.w};
      #pragma unroll
      for(int i=0;i<4;i++)
        #pragma unroll
        for(int j=0;j<8;j++) acc[i][j] += av[i]*bv[j];
    }
    __syncthreads();
  }
  #pragma unroll
  for(int i=0;i<4;i++){
    int m = m0 + ty*4 + i;
    bool valid = (m < M);
    float v[8]; float s=0.f, q=0.f;
    #pragma unroll
    for(int j=0;j<8;j++){
      int c = (j<4) ? tx*4+j : 128 + tx*4 + (j-4);
      float t = acc[i][j];
      if(bias) t += bias[c];
      if(res && valid) t += res[(size_t)m*C_ + c];
      v[j] = t; s += t; q += t*t;
    }
    #pragma unroll
    for(int off=16; off; off>>=1){ s += __shfl_xor(s, off, 32); q += __shfl_xor(q, off, 32); }
    float mean = s*(1.f/256.f);
    float rstd = rsqrtf(q*(1.f/256.f) - mean*mean + 1e-5f);
    if(valid){
      float o[8];
      #pragma unroll
      for(int j=0;j<8;j++){
        int c = (j<4) ? tx*4+j : 128 + tx*4 + (j-4);
        float t = (v[j]-mean)*rstd*g[c] + b[c];
        if(act==1) t = fmaxf(t, 0.f);
        else if(act==2) t = 1.f/(1.f + __expf(-t));
        o[j] = t;
      }
      float4 o0 = {o[0],o[1],o[2],o[3]}, o1 = {o[4],o[5],o[6],o[7]};
      *(float4*)&out[(size_t)m*C_ + tx*4] = o0;
      *(float4*)&out[(size_t)m*C_ + 128 + tx*4] = o1;
    }
  }
}

// ---------------- gate = i_in * p_in ----------------
__global__ __launch_bounds__(256) void k_gate(const float* __restrict__ inp, const float* __restrict__ params,
                                              float* __restrict__ gate){
  int i = blockIdx.x*256 + threadIdx.x;
  if(i >= ROWS_*C_) return;
  int c = i & 255, r = i >> 8;
  int np = r / 9;
  gate[i] = inp[(size_t)r*512 + c] * params[(size_t)np*512 + c];
}

// ---------------- block LN helper ----------------
__device__ __forceinline__ void block_stats(float v, float* red, int slot, float& mean, float& rstd){
  float s = v, q = v*v;
  #pragma unroll
  for(int off=32; off; off>>=1){ s += __shfl_xor(s, off, 64); q += __shfl_xor(q, off, 64); }
  int wid = threadIdx.x >> 6;
  if((threadIdx.x & 63) == 0){ red[slot + wid] = s; red[slot + 4 + wid] = q; }
  __syncthreads();
  s = red[slot+0]+red[slot+1]+red[slot+2]+red[slot+3];
  q = red[slot+4]+red[slot+5]+red[slot+6]+red[slot+7];
  mean = s*(1.f/256.f);
  rstd = rsqrtf(q*(1.f/256.f) - mean*mean + 1e-5f);
}

// ---------------- feat = ug * LN(p_out) + ig * LN(i_out) ----------------
__global__ __launch_bounds__(256) void k_combine(const float* __restrict__ params, const float* __restrict__ inp,
  const float* __restrict__ ug, const float* __restrict__ ig,
  const float* __restrict__ nout_g, const float* __restrict__ nout_b,
  const float* __restrict__ inout_g, const float* __restrict__ inout_b,
  float* __restrict__ feat)
{
  __shared__ float red[16];
  int r = blockIdx.x;           // np*9+kk
  int np = r / 9;
  int c = threadIdx.x;
  float pv = params[(size_t)np*512 + 256 + c];
  float mean, rstd;
  block_stats(pv, red, 0, mean, rstd);
  float pn = (pv - mean)*rstd*nout_g[c] + nout_b[c];
  float iv = inp[(size_t)r*512 + 256 + c];
  float mean2, rstd2;
  block_stats(iv, red, 8, mean2, rstd2);
  float iw = (iv - mean2)*rstd2*inout_g[c] + inout_b[c];
  size_t o = (size_t)r*C_ + c;
  feat[o] = ug[o]*pn + ig[o]*iw;
}

// ---------------- attention v2: block per (qtile=10, head, n) = 160 blocks ----------------
// LDS-staged Q tile (pre-scaled), K/V in 25-row tiles, S in LDS, block softmax,
// register-accumulated S@V. All global reads are 288-contiguous rows (coalesced).
__global__ __launch_bounds__(256) void k_attn2(const float* __restrict__ qkv, float* __restrict__ attnO){
  const int qt = blockIdx.x, h = blockIdx.y, n = blockIdx.z;
  const int q0 = qt*10;
  const int tid = threadIdx.x;
  __shared__ float Qs[10][292];
  __shared__ float KVs[25][292];
  __shared__ float Ss[10][104];
  const float scale = 0.05892556509887896f;   // 1/sqrt(288)
  const size_t base = (size_t)n*P_*6912 + (size_t)h*DH_;
  // load+scale Q tile
  for(int i=tid; i<10*DH_; i+=256){
    int qi = i/DH_, d = i - qi*DH_;
    Qs[qi][d] = qkv[base + (size_t)(q0+qi)*6912 + d] * scale;
  }
  // S = Q K^T, kp tiles of 25
  for(int kt=0; kt<4; kt++){
    int kp0 = kt*25;
    __syncthreads();
    for(int i=tid; i<25*DH_; i+=256){
      int ki = i/DH_, d = i - ki*DH_;
      KVs[ki][d] = qkv[base + (size_t)(kp0+ki)*6912 + E_ + d];
    }
    __syncthreads();
    if(tid < 250){
      int qi = tid/25, ki = tid - qi*25;
      float s = 0.f;
      #pragma unroll 9
      for(int d=0; d<DH_; d+=4){
        const float4 a = *(const float4*)&Qs[qi][d];
        const float4 b = *(const float4*)&KVs[ki][d];
        s += a.x*b.x + a.y*b.y + a.z*b.z + a.w*b.w;
      }
      Ss[qi][kp0+ki] = s;
    }
  }
  __syncthreads();
  // softmax per row (wave per row, rows strided by 4 waves)
  {
    int w = tid >> 6, lane = tid & 63;
    for(int r=w; r<10; r+=4){
      float v0 = (lane < 100) ? Ss[r][lane] : -1e30f;
      float v1 = (lane < 36)  ? Ss[r][64+lane] : -1e30f;
      float m = fmaxf(v0, v1);
      #pragma unroll
      for(int off=32; off; off>>=1) m = fmaxf(m, __shfl_xor(m, off, 64));
      float e0 = (lane < 100) ? __expf(v0-m) : 0.f;
      float e1 = (lane < 36)  ? __expf(v1-m) : 0.f;
      float s = e0 + e1;
      #pragma unroll
      for(int off=32; off; off>>=1) s += __shfl_xor(s, off, 64);
      float inv = 1.f/s;
      if(lane < 100) Ss[r][lane] = e0*inv;
      if(lane < 36)  Ss[r][64+lane] = e1*inv;
    }
  }
  // O = S @ V, reusing KVs for V tiles; per-thread register accumulators
  float acc[12];
  #pragma unroll
  for(int j=0;j<12;j++) acc[j]=0.f;
  for(int kt=0; kt<4; kt++){
    int kp0 = kt*25;
    __syncthreads();
    for(int i=tid; i<25*DH_; i+=256){
      int ki = i/DH_, d = i - ki*DH_;
      KVs[ki][d] = qkv[base + (size_t)(kp0+ki)*6912 + 2*E_ + d];
    }
    __syncthreads();
    int j = 0;
    for(int i=tid; i<10*DH_; i+=256, j++){
      int qi = i/DH_, d = i - qi*DH_;
      float s = acc[j];
      #pragma unroll
      for(int ki=0; ki<25; ki++) s += Ss[qi][kp0+ki]*KVs[ki][d];
      acc[j] = s;
    }
  }
  {
    int j = 0;
    for(int i=tid; i<10*DH_; i+=256, j++){
      int qi = i/DH_, d = i - qi*DH_;
      attnO[(size_t)(n*P_ + q0 + qi)*E_ + h*DH_ + d] = acc[j];
    }
  }
}

// ---------------- obj1 = LN(obj0 + tproj) over E=2304 ----------------
__global__ __launch_bounds__(256) void k_add_ln2304(const float* __restrict__ obj0, const float* __restrict__ tp,
  const float* __restrict__ g, const float* __restrict__ b, float* __restrict__ out)
{
  __shared__ float red[8];
  int row = blockIdx.x;
  float v[9]; float s=0.f, q=0.f;
  #pragma unroll
  for(int j=0;j<9;j++){
    int e = threadIdx.x + j*256;
    float t = obj0[(size_t)row*E_ + e] + tp[(size_t)row*E_ + e];
    v[j]=t; s+=t; q+=t*t;
  }
  #pragma unroll
  for(int off=32; off; off>>=1){ s += __shfl_xor(s, off, 64); q += __shfl_xor(q, off, 64); }
  int wid = threadIdx.x>>6;
  if((threadIdx.x&63)==0){ red[wid]=s; red[4+wid]=q; }
  __syncthreads();
  s = red[0]+red[1]+red[2]+red[3]; q = red[4]+red[5]+red[6]+red[7];
  float mean = s*(1.f/2304.f);
  float rstd = rsqrtf(q*(1.f/2304.f) - mean*mean + 1e-5f);
  #pragma unroll
  for(int j=0;j<9;j++){
    int e = threadIdx.x + j*256;
    out[(size_t)row*E_ + e] = (v[j]-mean)*rstd*g[e] + b[e];
  }
}

// ---------------- obj_kernels output transpose ----------------
__global__ __launch_bounds__(256) void k_objk(const float* __restrict__ obj2, float* __restrict__ outk){
  int i = blockIdx.x*256 + threadIdx.x;
  if(i >= ROWS_*C_) return;
  int kk = i % 9; int t = i / 9; int c = t & 255; int np = t >> 8;
  outk[i] = obj2[((size_t)np*9 + kk)*C_ + c];
}

// ---------------- dynamic conv ----------------
__global__ __launch_bounds__(256) void k_conv(const float* __restrict__ x, const float* __restrict__ ker,
                                              float* __restrict__ out){
  const int wt = blockIdx.x, ht = blockIdx.y, pz = blockIdx.z;
  const int n = pz / 7, pt = pz - n*7;
  const int tid = threadIdx.x;
  const int wg = tid & 7, pg = (tid>>3)&3, hi = tid>>5;
  const int w0 = wt*64, h0 = ht*8;
  __shared__ float xs[8][10][68];
  __shared__ float ks[8][16][12];
  float acc[4][8] = {};
  for(int c0=0; c0<C_; c0+=8){
    for(int i = tid; i < 8*10*66; i += 256){
      int wx = i % 66; int t = i / 66; int hy = t % 10; int ci = t / 10;
      int hh = h0 - 1 + hy, ww = w0 - 1 + wx;
      float v = 0.f;
      if(hh >= 0 && hh < H_ && ww >= 0 && ww < W_)
        v = x[(((size_t)n*C_ + c0+ci)*H_ + hh)*W_ + ww];
      xs[ci][hy][wx] = v;
    }
    for(int i = tid; i < 16*9*8; i += 256){
      int ci = i % 8; int t = i / 8; int tap = t % 9; int pp = t / 9;
      int p = pt*16 + pp;
      float v = 0.f;
      if(p < P_) v = ker[((size_t)(n*P_+p)*9 + tap)*C_ + c0 + ci];
      ks[ci][pp][tap] = v;
    }
    __syncthreads();
    for(int ci=0; ci<8; ci++){
      #pragma unroll
      for(int ky=0; ky<3; ky++){
        float xv[10];
        #pragma unroll
        for(int t=0;t<10;t++) xv[t] = xs[ci][hi+ky][wg*8 + t];
        #pragma unroll
        for(int ii=0; ii<4; ii++){
          int pp = pg*4 + ii;
          float k0 = ks[ci][pp][ky*3+0];
          float k1 = ks[ci][pp][ky*3+1];
          float k2 = ks[ci][pp][ky*3+2];
          #pragma unroll
          for(int j=0;j<8;j++)
            acc[ii][j] += k0*xv[j] + k1*xv[j+1] + k2*xv[j+2];
        }
      }
    }
    __syncthreads();
  }
  int h = h0 + hi;
  #pragma unroll
  for(int ii=0;ii<4;ii++){
    int p = pt*16 + pg*4 + ii;
    if(p < P_){
      float* op = &out[((size_t)(n*P_+p)*H_ + h)*W_ + w0 + wg*8];
      float4 o0 = {acc[ii][0],acc[ii][1],acc[ii][2],acc[ii][3]};
      float4 o1 = {acc[ii][4],acc[ii][5],acc[ii][6],acc[ii][7]};
      *(float4*)op = o0;
      *(float4*)(op+4) = o1;
    }
  }
}

extern "C" void kernel_launch(void* const* d_in, const int* in_sizes, int n_in,
                              void* d_out, int out_size, void* d_ws, size_t ws_size,
                              hipStream_t stream)
{
  (void)in_sizes; (void)n_in; (void)out_size; (void)ws_size;
  const float* x          = (const float*)d_in[0];
  const float* prop       = (const float*)d_in[1];
  const float* mask_pred  = (const float*)d_in[2];
  const float* ku_dyn_w   = (const float*)d_in[3];
  const float* ku_dyn_b   = (const float*)d_in[4];
  const float* ku_in_w    = (const float*)d_in[5];
  const float* ku_in_b    = (const float*)d_in[6];
  const float* ku_ig_w    = (const float*)d_in[7];
  const float* ku_ig_b    = (const float*)d_in[8];
  const float* ku_ug_w    = (const float*)d_in[9];
  const float* ku_ug_b    = (const float*)d_in[10];
  const float* ku_nin_g   = (const float*)d_in[11];
  const float* ku_nin_b   = (const float*)d_in[12];
  const float* ku_nout_g  = (const float*)d_in[13];
  const float* ku_nout_b  = (const float*)d_in[14];
  const float* ku_inin_g  = (const float*)d_in[15];
  const float* ku_inin_b  = (const float*)d_in[16];
  const float* ku_inout_g = (const float*)d_in[17];
  const float* ku_inout_b = (const float*)d_in[18];
  const float* ku_fc_w    = (const float*)d_in[19];
  const float* ku_fc_b    = (const float*)d_in[20];
  const float* ku_fcn_g   = (const float*)d_in[21];
  const float* ku_fcn_b   = (const float*)d_in[22];
  const float* attn_in_w  = (const float*)d_in[23];
  const float* attn_in_b  = (const float*)d_in[24];
  const float* attn_out_w = (const float*)d_in[25];
  const float* attn_out_b = (const float*)d_in[26];
  const float* attn_ln_g  = (const float*)d_in[27];
  const float* attn_ln_b  = (const float*)d_in[28];
  const float* ffn_w1     = (const float*)d_in[29];
  const float* ffn_b1     = (const float*)d_in[30];
  const float* ffn_w2     = (const float*)d_in[31];
  const float* ffn_b2     = (const float*)d_in[32];
  const float* ffn_ln_g   = (const float*)d_in[33];
  const float* ffn_ln_b   = (const float*)d_in[34];
  const float* mask_fc_ws = (const float*)d_in[35];
  const float* mask_fc_ln_g = (const float*)d_in[36];
  const float* mask_fc_ln_b = (const float*)d_in[37];
  const float* fc_mask_w  = (const float*)d_in[38];
  const float* fc_mask_b  = (const float*)d_in[39];

  float* ws = (float*)d_ws;
  float* sig     = ws;
  float* hbuf    = ws;
  float* partial = ws + 4915200;
  float* qkv     = ws + 4915200;
  float* attnO   = ws + 4915200 + 1382400;
  float* tproj   = ws + 4915200 + 1843200;
  float* xfeat   = ws + 9830400;
  float* params  = xfeat + 51200;
  float* pf      = params + 102400;
  float* inp     = pf + 460800;
  float* gate    = inp + 921600;
  float* ig      = gate + 460800;
  float* ug      = ig + 460800;
  float* feat    = ug + 460800;
  float* obj0    = feat + 460800;
  float* obj1    = obj0 + 460800;
  float* obj2    = obj1 + 460800;
  float* mf1     = obj2 + 460800;
  float* mf2     = mf1 + 460800;
  float* mfF     = mf2 + 460800;

  float* out_masks = (float*)d_out;
  float* out_kern  = out_masks + (size_t)N_*P_*HW_;

  k_softmax<<<192, 256, 0, stream>>>(mask_pred, sig);
  k_permute_pf<<<1800, 256, 0, stream>>>(prop, pf);
  k_xfeat1<<<dim3(96,8,2), 256, 0, stream>>>(sig, x, partial);
  k_xfeat2<<<200, 256, 0, stream>>>(partial, xfeat);
  k_gemm<<<dim3(8,4),  256, 0, stream>>>(xfeat, ku_dyn_w, ku_dyn_b, params, 200, 512, 256, 0);
  k_gemm<<<dim3(8,29), 256, 0, stream>>>(pf, ku_in_w, ku_in_b, inp, 1800, 512, 256, 0);
  k_gate<<<1800, 256, 0, stream>>>(inp, params, gate);
  k_gemm_ln<<<57, 256, 0, stream>>>(gate, ku_ig_w, ku_ig_b, nullptr, ku_inin_g, ku_inin_b, ig, 1800, 256, 2);
  k_gemm_ln<<<57, 256, 0, stream>>>(gate, ku_ug_w, ku_ug_b, nullptr, ku_nin_g, ku_nin_b, ug, 1800, 256, 2);
  k_combine<<<1800, 256, 0, stream>>>(params, inp, ug, ig, ku_nout_g, ku_nout_b, ku_inout_g, ku_inout_b, feat);
  k_gemm_ln<<<57, 256, 0, stream>>>(feat, ku_fc_w, ku_fc_b, nullptr, ku_fcn_g, ku_fcn_b, obj0, 1800, 256, 1);
  k_gemm<<<dim3(108,4), 256, 0, stream>>>(obj0, attn_in_w, attn_in_b, qkv, 200, 6912, 2304, 0);
  k_attn2<<<dim3(10,8,2), 256, 0, stream>>>(qkv, attnO);
  k_gemm<<<dim3(36,4), 256, 0, stream>>>(attnO, attn_out_w, attn_out_b, tproj, 200, 2304, 2304, 0);
  k_add_ln2304<<<200, 256, 0, stream>>>(obj0, tproj, attn_ln_g, attn_ln_b, obj1);
  k_gemm<<<dim3(32,29), 256, 0, stream>>>(obj1, ffn_w1, ffn_b1, hbuf, 1800, 2048, 256, 1);
  k_gemm_ln<<<57, 256, 0, stream>>>(hbuf, ffn_w2, ffn_b2, obj1, ffn_ln_g, ffn_ln_b, obj2, 1800, 2048, 0);
  k_gemm_ln<<<57, 256, 0, stream>>>(obj2, mask_fc_ws,          nullptr, nullptr, mask_fc_ln_g,       mask_fc_ln_b,       mf1, 1800, 256, 1);
  k_gemm_ln<<<57, 256, 0, stream>>>(mf1,  mask_fc_ws + 65536,  nullptr, nullptr, mask_fc_ln_g + 256, mask_fc_ln_b + 256, mf2, 1800, 256, 1);
  k_gemm_ln<<<57, 256, 0, stream>>>(mf2,  mask_fc_ws + 131072, nullptr, nullptr, mask_fc_ln_g + 512, mask_fc_ln_b + 512, mf1, 1800, 256, 1);
  k_gemm<<<dim3(4,29), 256, 0, stream>>>(mf1, fc_mask_w, fc_mask_b, mfF, 1800, 256, 256, 0);
  k_objk<<<1800, 256, 0, stream>>>(obj2, out_kern);
  k_conv<<<dim3(3,16,14), 256, 0, stream>>>(x, mfF, out_masks);
}

// Round 3
// 2074.209 us; speedup vs baseline: 1.7435x; 1.2523x over previous
//
#include <hip/hip_runtime.h>
#include <hip/hip_bf16.h>

#define N_ 2
#define P_ 100
#define C_ 256
#define H_ 128
#define W_ 192
#define HW_ 24576
#define KK_ 9
#define E_ 2304
#define NH_ 8
#define DH_ 288
#define FFN_ 2048
#define NP_ 200
#define ROWS_ 1800   // NP_*KK_

typedef __attribute__((ext_vector_type(8))) __bf16 bf16x8;
typedef __attribute__((ext_vector_type(4))) float f32x4;

__device__ __forceinline__ float bf2f(unsigned short u){
  return __uint_as_float(((unsigned)u) << 16);
}

// ---------------- softmax over P axis of mask_preds ----------------
__global__ __launch_bounds__(256) void k_softmax(const float* __restrict__ mp, float* __restrict__ sig){
  int idx = blockIdx.x*256 + threadIdx.x;
  if(idx >= N_*HW_) return;
  int n = idx / HW_, hw = idx - n*HW_;
  const float* base = mp + (size_t)n*P_*HW_ + hw;
  float m = -1e30f;
  for(int p=0;p<P_;p++) m = fmaxf(m, base[(size_t)p*HW_]);
  float s = 0.f;
  for(int p=0;p<P_;p++) s += __expf(base[(size_t)p*HW_] - m);
  float inv = 1.f/s;
  float* ob = sig + (size_t)n*P_*HW_ + hw;
  for(int p=0;p<P_;p++) ob[(size_t)p*HW_] = __expf(base[(size_t)p*HW_] - m)*inv;
}

// ---------------- pf permute: pf[np][kk][c] = prop[n][p][c*9+kk] ----------------
__global__ __launch_bounds__(256) void k_permute_pf(const float* __restrict__ prop, float* __restrict__ pf){
  int i = blockIdx.x*256 + threadIdx.x;
  if(i >= ROWS_*C_) return;
  int c = i & 255;
  int r = i >> 8;            // np*9+kk
  int kk = r % 9, np = r / 9;
  pf[i] = prop[(size_t)np*E_ + c*KK_ + kk];
}

// ---------------- x_feat stage 1: split-K partials ----------------
__global__ __launch_bounds__(256) void k_xfeat1(const float* __restrict__ sig, const float* __restrict__ x,
                                                float* __restrict__ partial){
  int kb = blockIdx.x, cb = blockIdx.y, n = blockIdx.z;
  int tid = threadIdx.x;
  int c4 = tid & 7, pg = tid >> 3;
  __shared__ float sg[100][129];
  __shared__ __hip_bfloat16 xsb[128][36];
  float acc[4][4] = {};
  int hw0 = kb*256;
  for(int sc=0; sc<2; sc++){
    int hwb = hw0 + sc*128;
    for(int i=tid; i<100*128; i+=256){
      int p = i >> 7, k = i & 127;
      sg[p][k] = sig[((size_t)n*P_ + p)*HW_ + hwb + k];
    }
    for(int i=tid; i<32*128; i+=256){
      int cl = i >> 7, k = i & 127;
      xsb[k][cl] = __float2bfloat16(x[((size_t)n*C_ + cb*32 + cl)*HW_ + hwb + k]);
    }
    __syncthreads();
    #pragma unroll 4
    for(int k=0;k<128;k++){
      short4 raw = *(const short4*)&xsb[k][c4*4];
      float x0 = bf2f((unsigned short)raw.x);
      float x1 = bf2f((unsigned short)raw.y);
      float x2 = bf2f((unsigned short)raw.z);
      float x3 = bf2f((unsigned short)raw.w);
      #pragma unroll
      for(int j=0;j<4;j++){
        int p = pg + 32*j;
        if(p < P_){
          float sv = sg[p][k];
          acc[j][0] += sv*x0; acc[j][1] += sv*x1; acc[j][2] += sv*x2; acc[j][3] += sv*x3;
        }
      }
    }
    __syncthreads();
  }
  #pragma unroll
  for(int j=0;j<4;j++){
    int p = pg + 32*j;
    if(p < P_){
      float4 v = {acc[j][0],acc[j][1],acc[j][2],acc[j][3]};
      *(float4*)&partial[(((size_t)n*96 + kb)*P_ + p)*C_ + cb*32 + c4*4] = v;
    }
  }
}

// ---------------- x_feat stage 2: reduce over 96 chunks ----------------
__global__ __launch_bounds__(256) void k_xfeat2(const float* __restrict__ partial, float* __restrict__ xfeat){
  int np = blockIdx.x;
  int n = np / P_, p = np - n*P_;
  int c = threadIdx.x;
  float s = 0.f;
  for(int kb=0;kb<96;kb++) s += partial[(((size_t)n*96 + kb)*P_ + p)*C_ + c];
  xfeat[(size_t)np*C_ + c] = s;
}

// ---------------- generic tiled fp32 GEMM: out = act(A @ W^T + bias) ----------------
__global__ __launch_bounds__(256) void k_gemm(const float* __restrict__ A, const float* __restrict__ Wt,
    const float* __restrict__ bias, float* __restrict__ out, int M, int N, int K, int act)
{
  __shared__ float As[32][68];
  __shared__ float Bs[32][68];
  const int m0 = blockIdx.y*64, n0 = blockIdx.x*64;
  const int tid = threadIdx.x;
  const int tx = tid & 15, ty = tid >> 4;
  float acc[4][4] = {};
  for(int k0=0;k0<K;k0+=32){
    #pragma unroll
    for(int i=0;i<8;i++){
      int idx = tid + i*256;
      int r = idx >> 5, kk = idx & 31;
      int m = m0 + r;
      As[kk][r] = (m < M) ? A[(size_t)m*K + k0 + kk] : 0.f;
      Bs[kk][r] = Wt[(size_t)(n0 + r)*K + k0 + kk];
    }
    __syncthreads();
    #pragma unroll
    for(int k=0;k<32;k++){
      const float4 a = *(const float4*)&As[k][ty*4];
      const float4 b = *(const float4*)&Bs[k][tx*4];
      float av[4] = {a.x,a.y,a.z,a.w};
      float bv[4] = {b.x,b.y,b.z,b.w};
      #pragma unroll
      for(int i=0;i<4;i++)
        #pragma unroll
        for(int j=0;j<4;j++) acc[i][j] += av[i]*bv[j];
    }
    __syncthreads();
  }
  #pragma unroll
  for(int i=0;i<4;i++){
    int m = m0 + ty*4 + i;
    if(m < M){
      float v[4];
      #pragma unroll
      for(int j=0;j<4;j++){
        float t = acc[i][j];
        if(bias) t += bias[n0 + tx*4 + j];
        if(act == 1) t = fmaxf(t, 0.f);
        v[j] = t;
      }
      float4 o = {v[0],v[1],v[2],v[3]};
      *(float4*)&out[(size_t)m*N + n0 + tx*4] = o;
    }
  }
}

// ---------------- GEMM (N=256) + bias + residual + LayerNorm + act ----------------
__global__ __launch_bounds__(256) void k_gemm_ln(const float* __restrict__ A, const float* __restrict__ Wt,
    const float* __restrict__ bias, const float* __restrict__ res,
    const float* __restrict__ g, const float* __restrict__ b,
    float* __restrict__ out, int M, int K, int act)
{
  __shared__ float As[32][36];
  __shared__ float Bs[32][260];
  const int m0 = blockIdx.x*32;
  const int tid = threadIdx.x;
  const int tx = tid & 31, ty = tid >> 5;
  float acc[4][8] = {};
  for(int k0=0;k0<K;k0+=32){
    #pragma unroll
    for(int i=0;i<4;i++){
      int idx = tid + i*256;
      int r = idx >> 5, kk = idx & 31;
      int m = m0 + r;
      As[kk][r] = (m < M) ? A[(size_t)m*K + k0 + kk] : 0.f;
    }
    for(int i=0;i<32;i++){
      int idx = tid + i*256;
      int r = idx >> 5, kk = idx & 31;
      Bs[kk][r] = Wt[(size_t)r*K + k0 + kk];
    }
    __syncthreads();
    #pragma unroll
    for(int k=0;k<32;k++){
      const float4 a  = *(const float4*)&As[k][ty*4];
      const float4 b0 = *(const float4*)&Bs[k][tx*4];
      const float4 b1 = *(const float4*)&Bs[k][128 + tx*4];
      float av[4] = {a.x,a.y,a.z,a.w};
      float bv[8] = {b0.x,b0.y,b0.z,b0.w,b1.x,b1.y,b1.z,b1.w};
      #pragma unroll
      for(int i=0;i<4;i++)
        #pragma unroll
        for(int j=0;j<8;j++) acc[i][j] += av[i]*bv[j];
    }
    __syncthreads();
  }
  #pragma unroll
  for(int i=0;i<4;i++){
    int m = m0 + ty*4 + i;
    bool valid = (m < M);
    float v[8]; float s=0.f, q=0.f;
    #pragma unroll
    for(int j=0;j<8;j++){
      int c = (j<4) ? tx*4+j : 128 + tx*4 + (j-4);
      float t = acc[i][j];
      if(bias) t += bias[c];
      if(res && valid) t += res[(size_t)m*C_ + c];
      v[j] = t; s += t; q += t*t;
    }
    #pragma unroll
    for(int off=16; off; off>>=1){ s += __shfl_xor(s, off, 32); q += __shfl_xor(q, off, 32); }
    float mean = s*(1.f/256.f);
    float rstd = rsqrtf(q*(1.f/256.f) - mean*mean + 1e-5f);
    if(valid){
      float o[8];
      #pragma unroll
      for(int j=0;j<8;j++){
        int c = (j<4) ? tx*4+j : 128 + tx*4 + (j-4);
        float t = (v[j]-mean)*rstd*g[c] + b[c];
        if(act==1) t = fmaxf(t, 0.f);
        else if(act==2) t = 1.f/(1.f + __expf(-t));
        o[j] = t;
      }
      float4 o0 = {o[0],o[1],o[2],o[3]}, o1 = {o[4],o[5],o[6],o[7]};
      *(float4*)&out[(size_t)m*C_ + tx*4] = o0;
      *(float4*)&out[(size_t)m*C_ + 128 + tx*4] = o1;
    }
  }
}

// ---------------- gate = i_in * p_in ----------------
__global__ __launch_bounds__(256) void k_gate(const float* __restrict__ inp, const float* __restrict__ params,
                                              float* __restrict__ gate){
  int i = blockIdx.x*256 + threadIdx.x;
  if(i >= ROWS_*C_) return;
  int c = i & 255, r = i >> 8;
  int np = r / 9;
  gate[i] = inp[(size_t)r*512 + c] * params[(size_t)np*512 + c];
}

// ---------------- block LN helper ----------------
__device__ __forceinline__ void block_stats(float v, float* red, int slot, float& mean, float& rstd){
  float s = v, q = v*v;
  #pragma unroll
  for(int off=32; off; off>>=1){ s += __shfl_xor(s, off, 64); q += __shfl_xor(q, off, 64); }
  int wid = threadIdx.x >> 6;
  if((threadIdx.x & 63) == 0){ red[slot + wid] = s; red[slot + 4 + wid] = q; }
  __syncthreads();
  s = red[slot+0]+red[slot+1]+red[slot+2]+red[slot+3];
  q = red[slot+4]+red[slot+5]+red[slot+6]+red[slot+7];
  mean = s*(1.f/256.f);
  rstd = rsqrtf(q*(1.f/256.f) - mean*mean + 1e-5f);
}

// ---------------- feat = ug * LN(p_out) + ig * LN(i_out) ----------------
__global__ __launch_bounds__(256) void k_combine(const float* __restrict__ params, const float* __restrict__ inp,
  const float* __restrict__ ug, const float* __restrict__ ig,
  const float* __restrict__ nout_g, const float* __restrict__ nout_b,
  const float* __restrict__ inout_g, const float* __restrict__ inout_b,
  float* __restrict__ feat)
{
  __shared__ float red[16];
  int r = blockIdx.x;           // np*9+kk
  int np = r / 9;
  int c = threadIdx.x;
  float pv = params[(size_t)np*512 + 256 + c];
  float mean, rstd;
  block_stats(pv, red, 0, mean, rstd);
  float pn = (pv - mean)*rstd*nout_g[c] + nout_b[c];
  float iv = inp[(size_t)r*512 + 256 + c];
  float mean2, rstd2;
  block_stats(iv, red, 8, mean2, rstd2);
  float iw = (iv - mean2)*rstd2*inout_g[c] + inout_b[c];
  size_t o = (size_t)r*C_ + c;
  feat[o] = ug[o]*pn + ig[o]*iw;
}

// ---------------- attention v2 ----------------
__global__ __launch_bounds__(256) void k_attn2(const float* __restrict__ qkv, float* __restrict__ attnO){
  const int qt = blockIdx.x, h = blockIdx.y, n = blockIdx.z;
  const int q0 = qt*10;
  const int tid = threadIdx.x;
  __shared__ float Qs[10][292];
  __shared__ float KVs[25][292];
  __shared__ float Ss[10][104];
  const float scale = 0.05892556509887896f;   // 1/sqrt(288)
  const size_t base = (size_t)n*P_*6912 + (size_t)h*DH_;
  for(int i=tid; i<10*DH_; i+=256){
    int qi = i/DH_, d = i - qi*DH_;
    Qs[qi][d] = qkv[base + (size_t)(q0+qi)*6912 + d] * scale;
  }
  for(int kt=0; kt<4; kt++){
    int kp0 = kt*25;
    __syncthreads();
    for(int i=tid; i<25*DH_; i+=256){
      int ki = i/DH_, d = i - ki*DH_;
      KVs[ki][d] = qkv[base + (size_t)(kp0+ki)*6912 + E_ + d];
    }
    __syncthreads();
    if(tid < 250){
      int qi = tid/25, ki = tid - qi*25;
      float s = 0.f;
      #pragma unroll 9
      for(int d=0; d<DH_; d+=4){
        const float4 a = *(const float4*)&Qs[qi][d];
        const float4 b = *(const float4*)&KVs[ki][d];
        s += a.x*b.x + a.y*b.y + a.z*b.z + a.w*b.w;
      }
      Ss[qi][kp0+ki] = s;
    }
  }
  __syncthreads();
  {
    int w = tid >> 6, lane = tid & 63;
    for(int r=w; r<10; r+=4){
      float v0 = (lane < 100) ? Ss[r][lane] : -1e30f;
      float v1 = (lane < 36)  ? Ss[r][64+lane] : -1e30f;
      float m = fmaxf(v0, v1);
      #pragma unroll
      for(int off=32; off; off>>=1) m = fmaxf(m, __shfl_xor(m, off, 64));
      float e0 = (lane < 100) ? __expf(v0-m) : 0.f;
      float e1 = (lane < 36)  ? __expf(v1-m) : 0.f;
      float s = e0 + e1;
      #pragma unroll
      for(int off=32; off; off>>=1) s += __shfl_xor(s, off, 64);
      float inv = 1.f/s;
      if(lane < 100) Ss[r][lane] = e0*inv;
      if(lane < 36)  Ss[r][64+lane] = e1*inv;
    }
  }
  float acc[12];
  #pragma unroll
  for(int j=0;j<12;j++) acc[j]=0.f;
  for(int kt=0; kt<4; kt++){
    int kp0 = kt*25;
    __syncthreads();
    for(int i=tid; i<25*DH_; i+=256){
      int ki = i/DH_, d = i - ki*DH_;
      KVs[ki][d] = qkv[base + (size_t)(kp0+ki)*6912 + 2*E_ + d];
    }
    __syncthreads();
    int j = 0;
    for(int i=tid; i<10*DH_; i+=256, j++){
      int qi = i/DH_, d = i - qi*DH_;
      float s = acc[j];
      #pragma unroll
      for(int ki=0; ki<25; ki++) s += Ss[qi][kp0+ki]*KVs[ki][d];
      acc[j] = s;
    }
  }
  {
    int j = 0;
    for(int i=tid; i<10*DH_; i+=256, j++){
      int qi = i/DH_, d = i - qi*DH_;
      attnO[(size_t)(n*P_ + q0 + qi)*E_ + h*DH_ + d] = acc[j];
    }
  }
}

// ---------------- obj1 = LN(obj0 + tproj) over E=2304 ----------------
__global__ __launch_bounds__(256) void k_add_ln2304(const float* __restrict__ obj0, const float* __restrict__ tp,
  const float* __restrict__ g, const float* __restrict__ b, float* __restrict__ out)
{
  __shared__ float red[8];
  int row = blockIdx.x;
  float v[9]; float s=0.f, q=0.f;
  #pragma unroll
  for(int j=0;j<9;j++){
    int e = threadIdx.x + j*256;
    float t = obj0[(size_t)row*E_ + e] + tp[(size_t)row*E_ + e];
    v[j]=t; s+=t; q+=t*t;
  }
  #pragma unroll
  for(int off=32; off; off>>=1){ s += __shfl_xor(s, off, 64); q += __shfl_xor(q, off, 64); }
  int wid = threadIdx.x>>6;
  if((threadIdx.x&63)==0){ red[wid]=s; red[4+wid]=q; }
  __syncthreads();
  s = red[0]+red[1]+red[2]+red[3]; q = red[4]+red[5]+red[6]+red[7];
  float mean = s*(1.f/2304.f);
  float rstd = rsqrtf(q*(1.f/2304.f) - mean*mean + 1e-5f);
  #pragma unroll
  for(int j=0;j<9;j++){
    int e = threadIdx.x + j*256;
    out[(size_t)row*E_ + e] = (v[j]-mean)*rstd*g[e] + b[e];
  }
}

// ---------------- obj_kernels output transpose ----------------
__global__ __launch_bounds__(256) void k_objk(const float* __restrict__ obj2, float* __restrict__ outk){
  int i = blockIdx.x*256 + threadIdx.x;
  if(i >= ROWS_*C_) return;
  int kk = i % 9; int t = i / 9; int c = t & 255; int np = t >> 8;
  outk[i] = obj2[((size_t)np*9 + kk)*C_ + c];
}

// ---------------- dynamic conv via implicit-GEMM bf16 MFMA ----------------
// grid dim3(3, 32, 4): wt (64 w), ht (4 h rows), z = n*2 + psplit (64 p each).
// Wave = one h row; 4 n-tiles (16 w) x NT p-tiles (16 p) MFMA accumulators.
// K = 9 taps x 256 c; c-slice (32) outer, tap inner. LDS: xs[hy][wx][ci] bf16
// (halo zero-filled), ks[tap][p][ci] bf16. Both fragment reads are ds_read_b128
// with bank-balanced starts ((16*col+4*quad)%32 partitions all 32 banks).
__global__ __launch_bounds__(256) void k_conv_mfma(const float* __restrict__ x, const float* __restrict__ ker,
                                                   float* __restrict__ out){
  const int wt = blockIdx.x, ht = blockIdx.y, z = blockIdx.z;
  const int n = z >> 1, ps = z & 1;
  const int pbase = ps*64;
  const int NT = ps ? 3 : 4;          // p-tiles in this split (112 total p slots, mask >=100)
  const int tid = threadIdx.x;
  const int hi = tid >> 6;            // wave id = output h row within block
  const int lane = tid & 63;
  const int col = lane & 15, quad = lane >> 4;
  const int w0 = wt*64, h0 = ht*4;

  __shared__ __bf16 xs[6][66][32];    // 25344 B
  __shared__ __bf16 ks[9][64][32];    // 36864 B

  f32x4 acc[4][4] = {};               // [ptile][ntile]
  const int npr = NT*16;              // p rows staged

  for(int c0=0; c0<C_; c0+=32){
    __syncthreads();
    // ---- stage x slice: 6 hy x 66 wx x 32 ci, zero halo ----
    for(int i=tid; i<1584; i+=256){
      int oct = i / 396;              // 0..3 -> ci = oct*8
      int rem = i - oct*396;
      int hy = rem / 66, wx = rem - hy*66;
      int hh = h0 - 1 + hy, ww = w0 - 1 + wx;
      bf16x8 v;
      if(hh >= 0 && hh < H_ && ww >= 0 && ww < W_){
        const float* xp = &x[(((size_t)n*C_ + c0 + oct*8)*H_ + hh)*W_ + ww];
        #pragma unroll
        for(int u=0;u<8;u++) v[u] = (__bf16)xp[(size_t)u*HW_];
      } else {
        #pragma unroll
        for(int u=0;u<8;u++) v[u] = (__bf16)0.f;
      }
      *(bf16x8*)&xs[hy][wx][oct*8] = v;
    }
    // ---- stage ker slice: 9 tap x npr p x 32 ci ----
    for(int i=tid; i<9*npr*4; i+=256){
      int oct = i & 3;
      int t = i >> 2;
      int tap = t / npr, pl = t - tap*npr;
      int p = pbase + pl;
      bf16x8 v;
      if(p < P_){
        const float* kp = &ker[((size_t)(n*P_+p)*9 + tap)*C_ + c0 + oct*8];
        #pragma unroll
        for(int u=0;u<8;u++) v[u] = (__bf16)kp[u];
      } else {
        #pragma unroll
        for(int u=0;u<8;u++) v[u] = (__bf16)0.f;
      }
      *(bf16x8*)&ks[tap][pl][oct*8] = v;
    }
    __syncthreads();
    // ---- MFMA: 9 taps x NT ptiles x 4 ntiles ----
    #pragma unroll
    for(int ky=0; ky<3; ky++){
      #pragma unroll
      for(int kx=0; kx<3; kx++){
        const int tap = ky*3 + kx;
        const int hy = hi + ky;
        bf16x8 b[4];
        #pragma unroll
        for(int t=0;t<4;t++) b[t] = *(const bf16x8*)&xs[hy][t*16 + col + kx][quad*8];
        #pragma unroll
        for(int pt=0; pt<4; pt++){
          if(pt < NT){
            bf16x8 a = *(const bf16x8*)&ks[tap][pt*16 + col][quad*8];
            #pragma unroll
            for(int t=0;t<4;t++)
              acc[pt][t] = __builtin_amdgcn_mfma_f32_16x16x32_bf16(a, b[t], acc[pt][t], 0, 0, 0);
          }
        }
      }
    }
  }
  // ---- epilogue: D[m=p][n=w]: p = pbase + pt*16 + quad*4 + r, w = w0 + t*16 + col ----
  const int h = h0 + hi;
  #pragma unroll
  for(int pt=0; pt<4; pt++){
    if(pt < NT){
      #pragma unroll
      for(int r=0;r<4;r++){
        int p = pbase + pt*16 + quad*4 + r;
        if(p < P_){
          float* op = &out[((size_t)(n*P_+p)*H_ + h)*W_ + w0 + col];
          #pragma unroll
          for(int t=0;t<4;t++) op[t*16] = acc[pt][t][r];
        }
      }
    }
  }
}

extern "C" void kernel_launch(void* const* d_in, const int* in_sizes, int n_in,
                              void* d_out, int out_size, void* d_ws, size_t ws_size,
                              hipStream_t stream)
{
  (void)in_sizes; (void)n_in; (void)out_size; (void)ws_size;
  const float* x          = (const float*)d_in[0];
  const float* prop       = (const float*)d_in[1];
  const float* mask_pred  = (const float*)d_in[2];
  const float* ku_dyn_w   = (const float*)d_in[3];
  const float* ku_dyn_b   = (const float*)d_in[4];
  const float* ku_in_w    = (const float*)d_in[5];
  const float* ku_in_b    = (const float*)d_in[6];
  const float* ku_ig_w    = (const float*)d_in[7];
  const float* ku_ig_b    = (const float*)d_in[8];
  const float* ku_ug_w    = (const float*)d_in[9];
  const float* ku_ug_b    = (const float*)d_in[10];
  const float* ku_nin_g   = (const float*)d_in[11];
  const float* ku_nin_b   = (const float*)d_in[12];
  const float* ku_nout_g  = (const float*)d_in[13];
  const float* ku_nout_b  = (const float*)d_in[14];
  const float* ku_inin_g  = (const float*)d_in[15];
  const float* ku_inin_b  = (const float*)d_in[16];
  const float* ku_inout_g = (const float*)d_in[17];
  const float* ku_inout_b = (const float*)d_in[18];
  const float* ku_fc_w    = (const float*)d_in[19];
  const float* ku_fc_b    = (const float*)d_in[20];
  const float* ku_fcn_g   = (const float*)d_in[21];
  const float* ku_fcn_b   = (const float*)d_in[22];
  const float* attn_in_w  = (const float*)d_in[23];
  const float* attn_in_b  = (const float*)d_in[24];
  const float* attn_out_w = (const float*)d_in[25];
  const float* attn_out_b = (const float*)d_in[26];
  const float* attn_ln_g  = (const float*)d_in[27];
  const float* attn_ln_b  = (const float*)d_in[28];
  const float* ffn_w1     = (const float*)d_in[29];
  const float* ffn_b1     = (const float*)d_in[30];
  const float* ffn_w2     = (const float*)d_in[31];
  const float* ffn_b2     = (const float*)d_in[32];
  const float* ffn_ln_g   = (const float*)d_in[33];
  const float* ffn_ln_b   = (const float*)d_in[34];
  const float* mask_fc_ws = (const float*)d_in[35];
  const float* mask_fc_ln_g = (const float*)d_in[36];
  const float* mask_fc_ln_b = (const float*)d_in[37];
  const float* fc_mask_w  = (const float*)d_in[38];
  const float* fc_mask_b  = (const float*)d_in[39];

  float* ws = (float*)d_ws;
  float* sig     = ws;
  float* hbuf    = ws;
  float* partial = ws + 4915200;
  float* qkv     = ws + 4915200;
  float* attnO   = ws + 4915200 + 1382400;
  float* tproj   = ws + 4915200 + 1843200;
  float* xfeat   = ws + 9830400;
  float* params  = xfeat + 51200;
  float* pf      = params + 102400;
  float* inp     = pf + 460800;
  float* gate    = inp + 921600;
  float* ig      = gate + 460800;
  float* ug      = ig + 460800;
  float* feat    = ug + 460800;
  float* obj0    = feat + 460800;
  float* obj1    = obj0 + 460800;
  float* obj2    = obj1 + 460800;
  float* mf1     = obj2 + 460800;
  float* mf2     = mf1 + 460800;
  float* mfF     = mf2 + 460800;

  float* out_masks = (float*)d_out;
  float* out_kern  = out_masks + (size_t)N_*P_*HW_;

  k_softmax<<<192, 256, 0, stream>>>(mask_pred, sig);
  k_permute_pf<<<1800, 256, 0, stream>>>(prop, pf);
  k_xfeat1<<<dim3(96,8,2), 256, 0, stream>>>(sig, x, partial);
  k_xfeat2<<<200, 256, 0, stream>>>(partial, xfeat);
  k_gemm<<<dim3(8,4),  256, 0, stream>>>(xfeat, ku_dyn_w, ku_dyn_b, params, 200, 512, 256, 0);
  k_gemm<<<dim3(8,29), 256, 0, stream>>>(pf, ku_in_w, ku_in_b, inp, 1800, 512, 256, 0);
  k_gate<<<1800, 256, 0, stream>>>(inp, params, gate);
  k_gemm_ln<<<57, 256, 0, stream>>>(gate, ku_ig_w, ku_ig_b, nullptr, ku_inin_g, ku_inin_b, ig, 1800, 256, 2);
  k_gemm_ln<<<57, 256, 0, stream>>>(gate, ku_ug_w, ku_ug_b, nullptr, ku_nin_g, ku_nin_b, ug, 1800, 256, 2);
  k_combine<<<1800, 256, 0, stream>>>(params, inp, ug, ig, ku_nout_g, ku_nout_b, ku_inout_g, ku_inout_b, feat);
  k_gemm_ln<<<57, 256, 0, stream>>>(feat, ku_fc_w, ku_fc_b, nullptr, ku_fcn_g, ku_fcn_b, obj0, 1800, 256, 1);
  k_gemm<<<dim3(108,4), 256, 0, stream>>>(obj0, attn_in_w, attn_in_b, qkv, 200, 6912, 2304, 0);
  k_attn2<<<dim3(10,8,2), 256, 0, stream>>>(qkv, attnO);
  k_gemm<<<dim3(36,4), 256, 0, stream>>>(attnO, attn_out_w, attn_out_b, tproj, 200, 2304, 2304, 0);
  k_add_ln2304<<<200, 256, 0, stream>>>(obj0, tproj, attn_ln_g, attn_ln_b, obj1);
  k_gemm<<<dim3(32,29), 256, 0, stream>>>(obj1, ffn_w1, ffn_b1, hbuf, 1800, 2048, 256, 1);
  k_gemm_ln<<<57, 256, 0, stream>>>(hbuf, ffn_w2, ffn_b2, obj1, ffn_ln_g, ffn_ln_b, obj2, 1800, 2048, 0);
  k_gemm_ln<<<57, 256, 0, stream>>>(obj2, mask_fc_ws,          nullptr, nullptr, mask_fc_ln_g,       mask_fc_ln_b,       mf1, 1800, 256, 1);
  k_gemm_ln<<<57, 256, 0, stream>>>(mf1,  mask_fc_ws + 65536,  nullptr, nullptr, mask_fc_ln_g + 256, mask_fc_ln_b + 256, mf2, 1800, 256, 1);
  k_gemm_ln<<<57, 256, 0, stream>>>(mf2,  mask_fc_ws + 131072, nullptr, nullptr, mask_fc_ln_g + 512, mask_fc_ln_b + 512, mf1, 1800, 256, 1);
  k_gemm<<<dim3(4,29), 256, 0, stream>>>(mf1, fc_mask_w, fc_mask_b, mfF, 1800, 256, 256, 0);
  k_objk<<<1800, 256, 0, stream>>>(obj2, out_kern);
  k_conv_mfma<<<dim3(3,32,4), 256, 0, stream>>>(x, mfF, out_masks);
}

// Round 4
// 1728.499 us; speedup vs baseline: 2.0922x; 1.2000x over previous
//
#include <hip/hip_runtime.h>
#include <hip/hip_bf16.h>

#define N_ 2
#define P_ 100
#define C_ 256
#define H_ 128
#define W_ 192
#define HW_ 24576
#define KK_ 9
#define E_ 2304
#define NH_ 8
#define DH_ 288
#define FFN_ 2048
#define NP_ 200
#define ROWS_ 1800   // NP_*KK_
#define XKC_ 64      // xfeat split-K chunks

typedef __attribute__((ext_vector_type(8))) __bf16 bf16x8;
typedef __attribute__((ext_vector_type(4))) float f32x4;

__device__ __forceinline__ float bf2f(unsigned short u){
  return __uint_as_float(((unsigned)u) << 16);
}

// ---------------- softmax over P axis of mask_preds ----------------
__global__ __launch_bounds__(256) void k_softmax(const float* __restrict__ mp, float* __restrict__ sig){
  int idx = blockIdx.x*256 + threadIdx.x;
  if(idx >= N_*HW_) return;
  int n = idx / HW_, hw = idx - n*HW_;
  const float* base = mp + (size_t)n*P_*HW_ + hw;
  float m = -1e30f;
  for(int p=0;p<P_;p++) m = fmaxf(m, base[(size_t)p*HW_]);
  float s = 0.f;
  for(int p=0;p<P_;p++) s += __expf(base[(size_t)p*HW_] - m);
  float inv = 1.f/s;
  float* ob = sig + (size_t)n*P_*HW_ + hw;
  for(int p=0;p<P_;p++) ob[(size_t)p*HW_] = __expf(base[(size_t)p*HW_] - m)*inv;
}

// ---------------- pf permute: pf[np][kk][c] = prop[n][p][c*9+kk] ----------------
__global__ __launch_bounds__(256) void k_permute_pf(const float* __restrict__ prop, float* __restrict__ pf){
  int i = blockIdx.x*256 + threadIdx.x;
  if(i >= ROWS_*C_) return;
  int c = i & 255;
  int r = i >> 8;            // np*9+kk
  int kk = r % 9, np = r / 9;
  pf[i] = prop[(size_t)np*E_ + c*KK_ + kk];
}

// ---------------- x_feat stage 1: bf16 MFMA split-K ----------------
// grid (ct 2, kb 64, n 2) = 256 blocks. Per block: BM=112 (7 mtiles, p<100 masked),
// BN=128 (8 ntiles), kchunk=384 (6 x BK=64). LDS rows padded +8 bf16 -> 2-way-free banks.
// Fragment convention identical to verified k_conv_mfma: A'[m=p][k], B'[n=c][k],
// D row=(quad*4+reg), col=lane&15.
__global__ __launch_bounds__(256) void k_xfeat1m(const float* __restrict__ sig, const float* __restrict__ x,
                                                 float* __restrict__ partial){
  const int ct = blockIdx.x, kb = blockIdx.y, n = blockIdx.z;
  const int hw0 = kb*384;
  const int tid = threadIdx.x;
  const int wid = tid >> 6, lane = tid & 63;
  const int col = lane & 15, quad = lane >> 4;
  const int wm = wid & 1, wn = wid >> 1;   // wm: mtile base 0/4, wn: ntile base 0/4
  const int MT = wm ? 3 : 4;               // mtiles 0-3 or 4-6
  __shared__ __bf16 As[112][72];
  __shared__ __bf16 Bs[128][72];
  f32x4 acc[4][4] = {};                    // [mt][nt]
  for(int k0=0; k0<384; k0+=64){
    __syncthreads();
    // stage A (sig): 112 rows x 64 k
    for(int i=tid; i<896; i+=256){
      int p = i >> 3, kg = i & 7;
      bf16x8 v;
      if(p < P_){
        const float* sp = &sig[((size_t)n*P_ + p)*HW_ + hw0 + k0 + kg*8];
        const float4 f0 = *(const float4*)sp;
        const float4 f1 = *(const float4*)(sp+4);
        v[0]=(__bf16)f0.x; v[1]=(__bf16)f0.y; v[2]=(__bf16)f0.z; v[3]=(__bf16)f0.w;
        v[4]=(__bf16)f1.x; v[5]=(__bf16)f1.y; v[6]=(__bf16)f1.z; v[7]=(__bf16)f1.w;
      } else {
        #pragma unroll
        for(int u=0;u<8;u++) v[u] = (__bf16)0.f;
      }
      *(bf16x8*)&As[p][kg*8] = v;
    }
    // stage B (x): 128 rows x 64 k
    for(int i=tid; i<1024; i+=256){
      int c = i >> 3, kg = i & 7;
      const float* xp = &x[((size_t)n*C_ + ct*128 + c)*HW_ + hw0 + k0 + kg*8];
      const float4 f0 = *(const float4*)xp;
      const float4 f1 = *(const float4*)(xp+4);
      bf16x8 v;
      v[0]=(__bf16)f0.x; v[1]=(__bf16)f0.y; v[2]=(__bf16)f0.z; v[3]=(__bf16)f0.w;
      v[4]=(__bf16)f1.x; v[5]=(__bf16)f1.y; v[6]=(__bf16)f1.z; v[7]=(__bf16)f1.w;
      *(bf16x8*)&Bs[c][kg*8] = v;
    }
    __syncthreads();
    #pragma unroll
    for(int ks=0; ks<2; ks++){
      bf16x8 b[4];
      #pragma unroll
      for(int t=0;t<4;t++) b[t] = *(const bf16x8*)&Bs[(wn*4+t)*16 + col][ks*32 + quad*8];
      #pragma unroll
      for(int mt=0; mt<4; mt++){
        if(mt < MT){
          bf16x8 a = *(const bf16x8*)&As[(wm*4+mt)*16 + col][ks*32 + quad*8];
          #pragma unroll
          for(int t=0;t<4;t++)
            acc[mt][t] = __builtin_amdgcn_mfma_f32_16x16x32_bf16(a, b[t], acc[mt][t], 0, 0, 0);
        }
      }
    }
  }
  // write partials: [n][kb][p][c]
  #pragma unroll
  for(int mt=0; mt<4; mt++){
    if(mt < MT){
      #pragma unroll
      for(int r=0;r<4;r++){
        int p = (wm*4+mt)*16 + quad*4 + r;
        if(p < P_){
          float* op = &partial[(((size_t)n*XKC_ + kb)*P_ + p)*C_ + ct*128 + wn*64 + col];
          #pragma unroll
          for(int t=0;t<4;t++) op[t*16] = acc[mt][t][r];
        }
      }
    }
  }
}

// ---------------- x_feat stage 2: reduce over XKC_ chunks ----------------
__global__ __launch_bounds__(256) void k_xfeat2(const float* __restrict__ partial, float* __restrict__ xfeat){
  int np = blockIdx.x;
  int n = np / P_, p = np - n*P_;
  int c = threadIdx.x;
  float s = 0.f;
  for(int kb=0;kb<XKC_;kb++) s += partial[(((size_t)n*XKC_ + kb)*P_ + p)*C_ + c];
  xfeat[(size_t)np*C_ + c] = s;
}

// ---------------- generic tiled fp32 GEMM: out = act(A @ W^T + bias) ----------------
__global__ __launch_bounds__(256) void k_gemm(const float* __restrict__ A, const float* __restrict__ Wt,
    const float* __restrict__ bias, float* __restrict__ out, int M, int N, int K, int act)
{
  __shared__ float As[32][68];
  __shared__ float Bs[32][68];
  const int m0 = blockIdx.y*64, n0 = blockIdx.x*64;
  const int tid = threadIdx.x;
  const int tx = tid & 15, ty = tid >> 4;
  float acc[4][4] = {};
  for(int k0=0;k0<K;k0+=32){
    #pragma unroll
    for(int i=0;i<8;i++){
      int idx = tid + i*256;
      int r = idx >> 5, kk = idx & 31;
      int m = m0 + r;
      As[kk][r] = (m < M) ? A[(size_t)m*K + k0 + kk] : 0.f;
      Bs[kk][r] = Wt[(size_t)(n0 + r)*K + k0 + kk];
    }
    __syncthreads();
    #pragma unroll
    for(int k=0;k<32;k++){
      const float4 a = *(const float4*)&As[k][ty*4];
      const float4 b = *(const float4*)&Bs[k][tx*4];
      float av[4] = {a.x,a.y,a.z,a.w};
      float bv[4] = {b.x,b.y,b.z,b.w};
      #pragma unroll
      for(int i=0;i<4;i++)
        #pragma unroll
        for(int j=0;j<4;j++) acc[i][j] += av[i]*bv[j];
    }
    __syncthreads();
  }
  #pragma unroll
  for(int i=0;i<4;i++){
    int m = m0 + ty*4 + i;
    if(m < M){
      float v[4];
      #pragma unroll
      for(int j=0;j<4;j++){
        float t = acc[i][j];
        if(bias) t += bias[n0 + tx*4 + j];
        if(act == 1) t = fmaxf(t, 0.f);
        v[j] = t;
      }
      float4 o = {v[0],v[1],v[2],v[3]};
      *(float4*)&out[(size_t)m*N + n0 + tx*4] = o;
    }
  }
}

// ---------------- GEMM (N=256) + bias + residual + LayerNorm + act ----------------
__global__ __launch_bounds__(256) void k_gemm_ln(const float* __restrict__ A, const float* __restrict__ Wt,
    const float* __restrict__ bias, const float* __restrict__ res,
    const float* __restrict__ g, const float* __restrict__ b,
    float* __restrict__ out, int M, int K, int act)
{
  __shared__ float As[32][36];
  __shared__ float Bs[32][260];
  const int m0 = blockIdx.x*32;
  const int tid = threadIdx.x;
  const int tx = tid & 31, ty = tid >> 5;
  float acc[4][8] = {};
  for(int k0=0;k0<K;k0+=32){
    #pragma unroll
    for(int i=0;i<4;i++){
      int idx = tid + i*256;
      int r = idx >> 5, kk = idx & 31;
      int m = m0 + r;
      As[kk][r] = (m < M) ? A[(size_t)m*K + k0 + kk] : 0.f;
    }
    for(int i=0;i<32;i++){
      int idx = tid + i*256;
      int r = idx >> 5, kk = idx & 31;
      Bs[kk][r] = Wt[(size_t)r*K + k0 + kk];
    }
    __syncthreads();
    #pragma unroll
    for(int k=0;k<32;k++){
      const float4 a  = *(const float4*)&As[k][ty*4];
      const float4 b0 = *(const float4*)&Bs[k][tx*4];
      const float4 b1 = *(const float4*)&Bs[k][128 + tx*4];
      float av[4] = {a.x,a.y,a.z,a.w};
      float bv[8] = {b0.x,b0.y,b0.z,b0.w,b1.x,b1.y,b1.z,b1.w};
      #pragma unroll
      for(int i=0;i<4;i++)
        #pragma unroll
        for(int j=0;j<8;j++) acc[i][j] += av[i]*bv[j];
    }
    __syncthreads();
  }
  #pragma unroll
  for(int i=0;i<4;i++){
    int m = m0 + ty*4 + i;
    bool valid = (m < M);
    float v[8]; float s=0.f, q=0.f;
    #pragma unroll
    for(int j=0;j<8;j++){
      int c = (j<4) ? tx*4+j : 128 + tx*4 + (j-4);
      float t = acc[i][j];
      if(bias) t += bias[c];
      if(res && valid) t += res[(size_t)m*C_ + c];
      v[j] = t; s += t; q += t*t;
    }
    #pragma unroll
    for(int off=16; off; off>>=1){ s += __shfl_xor(s, off, 32); q += __shfl_xor(q, off, 32); }
    float mean = s*(1.f/256.f);
    float rstd = rsqrtf(q*(1.f/256.f) - mean*mean + 1e-5f);
    if(valid){
      float o[8];
      #pragma unroll
      for(int j=0;j<8;j++){
        int c = (j<4) ? tx*4+j : 128 + tx*4 + (j-4);
        float t = (v[j]-mean)*rstd*g[c] + b[c];
        if(act==1) t = fmaxf(t, 0.f);
        else if(act==2) t = 1.f/(1.f + __expf(-t));
        o[j] = t;
      }
      float4 o0 = {o[0],o[1],o[2],o[3]}, o1 = {o[4],o[5],o[6],o[7]};
      *(float4*)&out[(size_t)m*C_ + tx*4] = o0;
      *(float4*)&out[(size_t)m*C_ + 128 + tx*4] = o1;
    }
  }
}

// ---------------- gate = i_in * p_in ----------------
__global__ __launch_bounds__(256) void k_gate(const float* __restrict__ inp, const float* __restrict__ params,
                                              float* __restrict__ gate){
  int i = blockIdx.x*256 + threadIdx.x;
  if(i >= ROWS_*C_) return;
  int c = i & 255, r = i >> 8;
  int np = r / 9;
  gate[i] = inp[(size_t)r*512 + c] * params[(size_t)np*512 + c];
}

// ---------------- block LN helper ----------------
__device__ __forceinline__ void block_stats(float v, float* red, int slot, float& mean, float& rstd){
  float s = v, q = v*v;
  #pragma unroll
  for(int off=32; off; off>>=1){ s += __shfl_xor(s, off, 64); q += __shfl_xor(q, off, 64); }
  int wid = threadIdx.x >> 6;
  if((threadIdx.x & 63) == 0){ red[slot + wid] = s; red[slot + 4 + wid] = q; }
  __syncthreads();
  s = red[slot+0]+red[slot+1]+red[slot+2]+red[slot+3];
  q = red[slot+4]+red[slot+5]+red[slot+6]+red[slot+7];
  mean = s*(1.f/256.f);
  rstd = rsqrtf(q*(1.f/256.f) - mean*mean + 1e-5f);
}

// ---------------- feat = ug * LN(p_out) + ig * LN(i_out) ----------------
__global__ __launch_bounds__(256) void k_combine(const float* __restrict__ params, const float* __restrict__ inp,
  const float* __restrict__ ug, const float* __restrict__ ig,
  const float* __restrict__ nout_g, const float* __restrict__ nout_b,
  const float* __restrict__ inout_g, const float* __restrict__ inout_b,
  float* __restrict__ feat)
{
  __shared__ float red[16];
  int r = blockIdx.x;           // np*9+kk
  int np = r / 9;
  int c = threadIdx.x;
  float pv = params[(size_t)np*512 + 256 + c];
  float mean, rstd;
  block_stats(pv, red, 0, mean, rstd);
  float pn = (pv - mean)*rstd*nout_g[c] + nout_b[c];
  float iv = inp[(size_t)r*512 + 256 + c];
  float mean2, rstd2;
  block_stats(iv, red, 8, mean2, rstd2);
  float iw = (iv - mean2)*rstd2*inout_g[c] + inout_b[c];
  size_t o = (size_t)r*C_ + c;
  feat[o] = ug[o]*pn + ig[o]*iw;
}

// ---------------- attention v2 ----------------
__global__ __launch_bounds__(256) void k_attn2(const float* __restrict__ qkv, float* __restrict__ attnO){
  const int qt = blockIdx.x, h = blockIdx.y, n = blockIdx.z;
  const int q0 = qt*10;
  const int tid = threadIdx.x;
  __shared__ float Qs[10][292];
  __shared__ float KVs[25][292];
  __shared__ float Ss[10][104];
  const float scale = 0.05892556509887896f;   // 1/sqrt(288)
  const size_t base = (size_t)n*P_*6912 + (size_t)h*DH_;
  for(int i=tid; i<10*DH_; i+=256){
    int qi = i/DH_, d = i - qi*DH_;
    Qs[qi][d] = qkv[base + (size_t)(q0+qi)*6912 + d] * scale;
  }
  for(int kt=0; kt<4; kt++){
    int kp0 = kt*25;
    __syncthreads();
    for(int i=tid; i<25*DH_; i+=256){
      int ki = i/DH_, d = i - ki*DH_;
      KVs[ki][d] = qkv[base + (size_t)(kp0+ki)*6912 + E_ + d];
    }
    __syncthreads();
    if(tid < 250){
      int qi = tid/25, ki = tid - qi*25;
      float s = 0.f;
      #pragma unroll 9
      for(int d=0; d<DH_; d+=4){
        const float4 a = *(const float4*)&Qs[qi][d];
        const float4 b = *(const float4*)&KVs[ki][d];
        s += a.x*b.x + a.y*b.y + a.z*b.z + a.w*b.w;
      }
      Ss[qi][kp0+ki] = s;
    }
  }
  __syncthreads();
  {
    int w = tid >> 6, lane = tid & 63;
    for(int r=w; r<10; r+=4){
      float v0 = (lane < 100) ? Ss[r][lane] : -1e30f;
      float v1 = (lane < 36)  ? Ss[r][64+lane] : -1e30f;
      float m = fmaxf(v0, v1);
      #pragma unroll
      for(int off=32; off; off>>=1) m = fmaxf(m, __shfl_xor(m, off, 64));
      float e0 = (lane < 100) ? __expf(v0-m) : 0.f;
      float e1 = (lane < 36)  ? __expf(v1-m) : 0.f;
      float s = e0 + e1;
      #pragma unroll
      for(int off=32; off; off>>=1) s += __shfl_xor(s, off, 64);
      float inv = 1.f/s;
      if(lane < 100) Ss[r][lane] = e0*inv;
      if(lane < 36)  Ss[r][64+lane] = e1*inv;
    }
  }
  float acc[12];
  #pragma unroll
  for(int j=0;j<12;j++) acc[j]=0.f;
  for(int kt=0; kt<4; kt++){
    int kp0 = kt*25;
    __syncthreads();
    for(int i=tid; i<25*DH_; i+=256){
      int ki = i/DH_, d = i - ki*DH_;
      KVs[ki][d] = qkv[base + (size_t)(kp0+ki)*6912 + 2*E_ + d];
    }
    __syncthreads();
    int j = 0;
    for(int i=tid; i<10*DH_; i+=256, j++){
      int qi = i/DH_, d = i - qi*DH_;
      float s = acc[j];
      #pragma unroll
      for(int ki=0; ki<25; ki++) s += Ss[qi][kp0+ki]*KVs[ki][d];
      acc[j] = s;
    }
  }
  {
    int j = 0;
    for(int i=tid; i<10*DH_; i+=256, j++){
      int qi = i/DH_, d = i - qi*DH_;
      attnO[(size_t)(n*P_ + q0 + qi)*E_ + h*DH_ + d] = acc[j];
    }
  }
}

// ---------------- obj1 = LN(obj0 + tproj) over E=2304 ----------------
__global__ __launch_bounds__(256) void k_add_ln2304(const float* __restrict__ obj0, const float* __restrict__ tp,
  const float* __restrict__ g, const float* __restrict__ b, float* __restrict__ out)
{
  __shared__ float red[8];
  int row = blockIdx.x;
  float v[9]; float s=0.f, q=0.f;
  #pragma unroll
  for(int j=0;j<9;j++){
    int e = threadIdx.x + j*256;
    float t = obj0[(size_t)row*E_ + e] + tp[(size_t)row*E_ + e];
    v[j]=t; s+=t; q+=t*t;
  }
  #pragma unroll
  for(int off=32; off; off>>=1){ s += __shfl_xor(s, off, 64); q += __shfl_xor(q, off, 64); }
  int wid = threadIdx.x>>6;
  if((threadIdx.x&63)==0){ red[wid]=s; red[4+wid]=q; }
  __syncthreads();
  s = red[0]+red[1]+red[2]+red[3]; q = red[4]+red[5]+red[6]+red[7];
  float mean = s*(1.f/2304.f);
  float rstd = rsqrtf(q*(1.f/2304.f) - mean*mean + 1e-5f);
  #pragma unroll
  for(int j=0;j<9;j++){
    int e = threadIdx.x + j*256;
    out[(size_t)row*E_ + e] = (v[j]-mean)*rstd*g[e] + b[e];
  }
}

// ---------------- obj_kernels output transpose ----------------
__global__ __launch_bounds__(256) void k_objk(const float* __restrict__ obj2, float* __restrict__ outk){
  int i = blockIdx.x*256 + threadIdx.x;
  if(i >= ROWS_*C_) return;
  int kk = i % 9; int t = i / 9; int c = t & 255; int np = t >> 8;
  outk[i] = obj2[((size_t)np*9 + kk)*C_ + c];
}

// ---------------- dynamic conv via implicit-GEMM bf16 MFMA ----------------
__global__ __launch_bounds__(256) void k_conv_mfma(const float* __restrict__ x, const float* __restrict__ ker,
                                                   float* __restrict__ out){
  const int wt = blockIdx.x, ht = blockIdx.y, z = blockIdx.z;
  const int n = z >> 1, ps = z & 1;
  const int pbase = ps*64;
  const int NT = ps ? 3 : 4;
  const int tid = threadIdx.x;
  const int hi = tid >> 6;
  const int lane = tid & 63;
  const int col = lane & 15, quad = lane >> 4;
  const int w0 = wt*64, h0 = ht*4;

  __shared__ __bf16 xs[6][66][32];
  __shared__ __bf16 ks[9][64][32];

  f32x4 acc[4][4] = {};
  const int npr = NT*16;

  for(int c0=0; c0<C_; c0+=32){
    __syncthreads();
    for(int i=tid; i<1584; i+=256){
      int oct = i / 396;
      int rem = i - oct*396;
      int hy = rem / 66, wx = rem - hy*66;
      int hh = h0 - 1 + hy, ww = w0 - 1 + wx;
      bf16x8 v;
      if(hh >= 0 && hh < H_ && ww >= 0 && ww < W_){
        const float* xp = &x[(((size_t)n*C_ + c0 + oct*8)*H_ + hh)*W_ + ww];
        #pragma unroll
        for(int u=0;u<8;u++) v[u] = (__bf16)xp[(size_t)u*HW_];
      } else {
        #pragma unroll
        for(int u=0;u<8;u++) v[u] = (__bf16)0.f;
      }
      *(bf16x8*)&xs[hy][wx][oct*8] = v;
    }
    for(int i=tid; i<9*npr*4; i+=256){
      int oct = i & 3;
      int t = i >> 2;
      int tap = t / npr, pl = t - tap*npr;
      int p = pbase + pl;
      bf16x8 v;
      if(p < P_){
        const float* kp = &ker[((size_t)(n*P_+p)*9 + tap)*C_ + c0 + oct*8];
        #pragma unroll
        for(int u=0;u<8;u++) v[u] = (__bf16)kp[u];
      } else {
        #pragma unroll
        for(int u=0;u<8;u++) v[u] = (__bf16)0.f;
      }
      *(bf16x8*)&ks[tap][pl][oct*8] = v;
    }
    __syncthreads();
    #pragma unroll
    for(int ky=0; ky<3; ky++){
      #pragma unroll
      for(int kx=0; kx<3; kx++){
        const int tap = ky*3 + kx;
        const int hy = hi + ky;
        bf16x8 b[4];
        #pragma unroll
        for(int t=0;t<4;t++) b[t] = *(const bf16x8*)&xs[hy][t*16 + col + kx][quad*8];
        #pragma unroll
        for(int pt=0; pt<4; pt++){
          if(pt < NT){
            bf16x8 a = *(const bf16x8*)&ks[tap][pt*16 + col][quad*8];
            #pragma unroll
            for(int t=0;t<4;t++)
              acc[pt][t] = __builtin_amdgcn_mfma_f32_16x16x32_bf16(a, b[t], acc[pt][t], 0, 0, 0);
          }
        }
      }
    }
  }
  const int h = h0 + hi;
  #pragma unroll
  for(int pt=0; pt<4; pt++){
    if(pt < NT){
      #pragma unroll
      for(int r=0;r<4;r++){
        int p = pbase + pt*16 + quad*4 + r;
        if(p < P_){
          float* op = &out[((size_t)(n*P_+p)*H_ + h)*W_ + w0 + col];
          #pragma unroll
          for(int t=0;t<4;t++) op[t*16] = acc[pt][t][r];
        }
      }
    }
  }
}

extern "C" void kernel_launch(void* const* d_in, const int* in_sizes, int n_in,
                              void* d_out, int out_size, void* d_ws, size_t ws_size,
                              hipStream_t stream)
{
  (void)in_sizes; (void)n_in; (void)out_size; (void)ws_size;
  const float* x          = (const float*)d_in[0];
  const float* prop       = (const float*)d_in[1];
  const float* mask_pred  = (const float*)d_in[2];
  const float* ku_dyn_w   = (const float*)d_in[3];
  const float* ku_dyn_b   = (const float*)d_in[4];
  const float* ku_in_w    = (const float*)d_in[5];
  const float* ku_in_b    = (const float*)d_in[6];
  const float* ku_ig_w    = (const float*)d_in[7];
  const float* ku_ig_b    = (const float*)d_in[8];
  const float* ku_ug_w    = (const float*)d_in[9];
  const float* ku_ug_b    = (const float*)d_in[10];
  const float* ku_nin_g   = (const float*)d_in[11];
  const float* ku_nin_b   = (const float*)d_in[12];
  const float* ku_nout_g  = (const float*)d_in[13];
  const float* ku_nout_b  = (const float*)d_in[14];
  const float* ku_inin_g  = (const float*)d_in[15];
  const float* ku_inin_b  = (const float*)d_in[16];
  const float* ku_inout_g = (const float*)d_in[17];
  const float* ku_inout_b = (const float*)d_in[18];
  const float* ku_fc_w    = (const float*)d_in[19];
  const float* ku_fc_b    = (const float*)d_in[20];
  const float* ku_fcn_g   = (const float*)d_in[21];
  const float* ku_fcn_b   = (const float*)d_in[22];
  const float* attn_in_w  = (const float*)d_in[23];
  const float* attn_in_b  = (const float*)d_in[24];
  const float* attn_out_w = (const float*)d_in[25];
  const float* attn_out_b = (const float*)d_in[26];
  const float* attn_ln_g  = (const float*)d_in[27];
  const float* attn_ln_b  = (const float*)d_in[28];
  const float* ffn_w1     = (const float*)d_in[29];
  const float* ffn_b1     = (const float*)d_in[30];
  const float* ffn_w2     = (const float*)d_in[31];
  const float* ffn_b2     = (const float*)d_in[32];
  const float* ffn_ln_g   = (const float*)d_in[33];
  const float* ffn_ln_b   = (const float*)d_in[34];
  const float* mask_fc_ws = (const float*)d_in[35];
  const float* mask_fc_ln_g = (const float*)d_in[36];
  const float* mask_fc_ln_b = (const float*)d_in[37];
  const float* fc_mask_w  = (const float*)d_in[38];
  const float* fc_mask_b  = (const float*)d_in[39];

  float* ws = (float*)d_ws;
  float* sig     = ws;
  float* hbuf    = ws;
  float* partial = ws + 4915200;
  float* qkv     = ws + 4915200;
  float* attnO   = ws + 4915200 + 1382400;
  float* tproj   = ws + 4915200 + 1843200;
  float* xfeat   = ws + 9830400;
  float* params  = xfeat + 51200;
  float* pf      = params + 102400;
  float* inp     = pf + 460800;
  float* gate    = inp + 921600;
  float* ig      = gate + 460800;
  float* ug      = ig + 460800;
  float* feat    = ug + 460800;
  float* obj0    = feat + 460800;
  float* obj1    = obj0 + 460800;
  float* obj2    = obj1 + 460800;
  float* mf1     = obj2 + 460800;
  float* mf2     = mf1 + 460800;
  float* mfF     = mf2 + 460800;

  float* out_masks = (float*)d_out;
  float* out_kern  = out_masks + (size_t)N_*P_*HW_;

  k_softmax<<<192, 256, 0, stream>>>(mask_pred, sig);
  k_permute_pf<<<1800, 256, 0, stream>>>(prop, pf);
  k_xfeat1m<<<dim3(2,XKC_,2), 256, 0, stream>>>(sig, x, partial);
  k_xfeat2<<<200, 256, 0, stream>>>(partial, xfeat);
  k_gemm<<<dim3(8,4),  256, 0, stream>>>(xfeat, ku_dyn_w, ku_dyn_b, params, 200, 512, 256, 0);
  k_gemm<<<dim3(8,29), 256, 0, stream>>>(pf, ku_in_w, ku_in_b, inp, 1800, 512, 256, 0);
  k_gate<<<1800, 256, 0, stream>>>(inp, params, gate);
  k_gemm_ln<<<57, 256, 0, stream>>>(gate, ku_ig_w, ku_ig_b, nullptr, ku_inin_g, ku_inin_b, ig, 1800, 256, 2);
  k_gemm_ln<<<57, 256, 0, stream>>>(gate, ku_ug_w, ku_ug_b, nullptr, ku_nin_g, ku_nin_b, ug, 1800, 256, 2);
  k_combine<<<1800, 256, 0, stream>>>(params, inp, ug, ig, ku_nout_g, ku_nout_b, ku_inout_g, ku_inout_b, feat);
  k_gemm_ln<<<57, 256, 0, stream>>>(feat, ku_fc_w, ku_fc_b, nullptr, ku_fcn_g, ku_fcn_b, obj0, 1800, 256, 1);
  k_gemm<<<dim3(108,4), 256, 0, stream>>>(obj0, attn_in_w, attn_in_b, qkv, 200, 6912, 2304, 0);
  k_attn2<<<dim3(10,8,2), 256, 0, stream>>>(qkv, attnO);
  k_gemm<<<dim3(36,4), 256, 0, stream>>>(attnO, attn_out_w, attn_out_b, tproj, 200, 2304, 2304, 0);
  k_add_ln2304<<<200, 256, 0, stream>>>(obj0, tproj, attn_ln_g, attn_ln_b, obj1);
  k_gemm<<<dim3(32,29), 256, 0, stream>>>(obj1, ffn_w1, ffn_b1, hbuf, 1800, 2048, 256, 1);
  k_gemm_ln<<<57, 256, 0, stream>>>(hbuf, ffn_w2, ffn_b2, obj1, ffn_ln_g, ffn_ln_b, obj2, 1800, 2048, 0);
  k_gemm_ln<<<57, 256, 0, stream>>>(obj2, mask_fc_ws,          nullptr, nullptr, mask_fc_ln_g,       mask_fc_ln_b,       mf1, 1800, 256, 1);
  k_gemm_ln<<<57, 256, 0, stream>>>(mf1,  mask_fc_ws + 65536,  nullptr, nullptr, mask_fc_ln_g + 256, mask_fc_ln_b + 256, mf2, 1800, 256, 1);
  k_gemm_ln<<<57, 256, 0, stream>>>(mf2,  mask_fc_ws + 131072, nullptr, nullptr, mask_fc_ln_g + 512, mask_fc_ln_b + 512, mf1, 1800, 256, 1);
  k_gemm<<<dim3(4,29), 256, 0, stream>>>(mf1, fc_mask_w, fc_mask_b, mfF, 1800, 256, 256, 0);
  k_objk<<<1800, 256, 0, stream>>>(obj2, out_kern);
  k_conv_mfma<<<dim3(3,32,4), 256, 0, stream>>>(x, mfF, out_masks);
}

// Round 5
// 924.160 us; speedup vs baseline: 3.9132x; 1.8703x over previous
//
#include <hip/hip_runtime.h>
#include <hip/hip_bf16.h>

#define N_ 2
#define P_ 100
#define C_ 256
#define H_ 128
#define W_ 192
#define HW_ 24576
#define KK_ 9
#define E_ 2304
#define NH_ 8
#define DH_ 288
#define FFN_ 2048
#define NP_ 200
#define ROWS_ 1800   // NP_*KK_
#define XKC_ 64      // xfeat split-K chunks

typedef __attribute__((ext_vector_type(8))) __bf16 bf16x8;
typedef __attribute__((ext_vector_type(4))) float f32x4;

// ---------------- softmax over P axis of mask_preds ----------------
__global__ __launch_bounds__(256) void k_softmax(const float* __restrict__ mp, float* __restrict__ sig){
  int idx = blockIdx.x*256 + threadIdx.x;
  if(idx >= N_*HW_) return;
  int n = idx / HW_, hw = idx - n*HW_;
  const float* base = mp + (size_t)n*P_*HW_ + hw;
  float m = -1e30f;
  for(int p=0;p<P_;p++) m = fmaxf(m, base[(size_t)p*HW_]);
  float s = 0.f;
  for(int p=0;p<P_;p++) s += __expf(base[(size_t)p*HW_] - m);
  float inv = 1.f/s;
  float* ob = sig + (size_t)n*P_*HW_ + hw;
  for(int p=0;p<P_;p++) ob[(size_t)p*HW_] = __expf(base[(size_t)p*HW_] - m)*inv;
}

// ---------------- pf permute: pf[np][kk][c] = prop[n][p][c*9+kk] ----------------
__global__ __launch_bounds__(256) void k_permute_pf(const float* __restrict__ prop, float* __restrict__ pf){
  int i = blockIdx.x*256 + threadIdx.x;
  if(i >= ROWS_*C_) return;
  int c = i & 255;
  int r = i >> 8;            // np*9+kk
  int kk = r % 9, np = r / 9;
  pf[i] = prop[(size_t)np*E_ + c*KK_ + kk];
}

// ---------------- x_feat stage 1: bf16 MFMA split-K ----------------
__global__ __launch_bounds__(256) void k_xfeat1m(const float* __restrict__ sig, const float* __restrict__ x,
                                                 float* __restrict__ partial){
  const int ct = blockIdx.x, kb = blockIdx.y, n = blockIdx.z;
  const int hw0 = kb*384;
  const int tid = threadIdx.x;
  const int wid = tid >> 6, lane = tid & 63;
  const int col = lane & 15, quad = lane >> 4;
  const int wm = wid & 1, wn = wid >> 1;
  const int MT = wm ? 3 : 4;
  __shared__ __bf16 As[112][72];
  __shared__ __bf16 Bs[128][72];
  f32x4 acc[4][4] = {};
  for(int k0=0; k0<384; k0+=64){
    __syncthreads();
    for(int i=tid; i<896; i+=256){
      int p = i >> 3, kg = i & 7;
      bf16x8 v;
      if(p < P_){
        const float* sp = &sig[((size_t)n*P_ + p)*HW_ + hw0 + k0 + kg*8];
        const float4 f0 = *(const float4*)sp;
        const float4 f1 = *(const float4*)(sp+4);
        v[0]=(__bf16)f0.x; v[1]=(__bf16)f0.y; v[2]=(__bf16)f0.z; v[3]=(__bf16)f0.w;
        v[4]=(__bf16)f1.x; v[5]=(__bf16)f1.y; v[6]=(__bf16)f1.z; v[7]=(__bf16)f1.w;
      } else {
        #pragma unroll
        for(int u=0;u<8;u++) v[u] = (__bf16)0.f;
      }
      *(bf16x8*)&As[p][kg*8] = v;
    }
    for(int i=tid; i<1024; i+=256){
      int c = i >> 3, kg = i & 7;
      const float* xp = &x[((size_t)n*C_ + ct*128 + c)*HW_ + hw0 + k0 + kg*8];
      const float4 f0 = *(const float4*)xp;
      const float4 f1 = *(const float4*)(xp+4);
      bf16x8 v;
      v[0]=(__bf16)f0.x; v[1]=(__bf16)f0.y; v[2]=(__bf16)f0.z; v[3]=(__bf16)f0.w;
      v[4]=(__bf16)f1.x; v[5]=(__bf16)f1.y; v[6]=(__bf16)f1.z; v[7]=(__bf16)f1.w;
      *(bf16x8*)&Bs[c][kg*8] = v;
    }
    __syncthreads();
    #pragma unroll
    for(int ks=0; ks<2; ks++){
      bf16x8 b[4];
      #pragma unroll
      for(int t=0;t<4;t++) b[t] = *(const bf16x8*)&Bs[(wn*4+t)*16 + col][ks*32 + quad*8];
      #pragma unroll
      for(int mt=0; mt<4; mt++){
        if(mt < MT){
          bf16x8 a = *(const bf16x8*)&As[(wm*4+mt)*16 + col][ks*32 + quad*8];
          #pragma unroll
          for(int t=0;t<4;t++)
            acc[mt][t] = __builtin_amdgcn_mfma_f32_16x16x32_bf16(a, b[t], acc[mt][t], 0, 0, 0);
        }
      }
    }
  }
  #pragma unroll
  for(int mt=0; mt<4; mt++){
    if(mt < MT){
      #pragma unroll
      for(int r=0;r<4;r++){
        int p = (wm*4+mt)*16 + quad*4 + r;
        if(p < P_){
          float* op = &partial[(((size_t)n*XKC_ + kb)*P_ + p)*C_ + ct*128 + wn*64 + col];
          #pragma unroll
          for(int t=0;t<4;t++) op[t*16] = acc[mt][t][r];
        }
      }
    }
  }
}

// ---------------- x_feat stage 2: reduce over XKC_ chunks ----------------
__global__ __launch_bounds__(256) void k_xfeat2(const float* __restrict__ partial, float* __restrict__ xfeat){
  int np = blockIdx.x;
  int n = np / P_, p = np - n*P_;
  int c = threadIdx.x;
  float s = 0.f;
  for(int kb=0;kb<XKC_;kb++) s += partial[(((size_t)n*XKC_ + kb)*P_ + p)*C_ + c];
  xfeat[(size_t)np*C_ + c] = s;
}

// ---------------- generic bf16 MFMA GEMM: out = act(A @ W^T + bias) ----------------
// BM=64, BN=128, BK=64. 4 waves: wm=wid&1 (m half), wn=wid>>1 (n half).
// Wave tile 32m x 64n = 2 mtiles x 4 ntiles. Fragment/LDS convention identical to
// verified k_xfeat1m/k_conv_mfma. Requires K%64==0, N%128==0; M masked.
__global__ __launch_bounds__(256) void k_gemm_mfma(const float* __restrict__ A, const float* __restrict__ Wt,
    const float* __restrict__ bias, float* __restrict__ out, int M, int N, int K, int act)
{
  const int n0 = blockIdx.x*128, m0 = blockIdx.y*64;
  const int tid = threadIdx.x;
  const int wid = tid >> 6, lane = tid & 63;
  const int col = lane & 15, quad = lane >> 4;
  const int wm = wid & 1, wn = wid >> 1;
  __shared__ __bf16 As[64][72];
  __shared__ __bf16 Bs[128][72];
  f32x4 acc[2][4] = {};
  for(int k0=0; k0<K; k0+=64){
    __syncthreads();
    for(int i=tid; i<512; i+=256){
      int r = i >> 3, kg = i & 7;
      int m = m0 + r;
      bf16x8 v;
      if(m < M){
        const float* ap = &A[(size_t)m*K + k0 + kg*8];
        const float4 f0 = *(const float4*)ap;
        const float4 f1 = *(const float4*)(ap+4);
        v[0]=(__bf16)f0.x; v[1]=(__bf16)f0.y; v[2]=(__bf16)f0.z; v[3]=(__bf16)f0.w;
        v[4]=(__bf16)f1.x; v[5]=(__bf16)f1.y; v[6]=(__bf16)f1.z; v[7]=(__bf16)f1.w;
      } else {
        #pragma unroll
        for(int u=0;u<8;u++) v[u] = (__bf16)0.f;
      }
      *(bf16x8*)&As[r][kg*8] = v;
    }
    for(int i=tid; i<1024; i+=256){
      int r = i >> 3, kg = i & 7;
      const float* wp = &Wt[(size_t)(n0 + r)*K + k0 + kg*8];
      const float4 f0 = *(const float4*)wp;
      const float4 f1 = *(const float4*)(wp+4);
      bf16x8 v;
      v[0]=(__bf16)f0.x; v[1]=(__bf16)f0.y; v[2]=(__bf16)f0.z; v[3]=(__bf16)f0.w;
      v[4]=(__bf16)f1.x; v[5]=(__bf16)f1.y; v[6]=(__bf16)f1.z; v[7]=(__bf16)f1.w;
      *(bf16x8*)&Bs[r][kg*8] = v;
    }
    __syncthreads();
    #pragma unroll
    for(int ks=0; ks<2; ks++){
      bf16x8 b[4], a[2];
      #pragma unroll
      for(int t=0;t<4;t++) b[t] = *(const bf16x8*)&Bs[(wn*4+t)*16 + col][ks*32 + quad*8];
      #pragma unroll
      for(int mt=0;mt<2;mt++) a[mt] = *(const bf16x8*)&As[(wm*2+mt)*16 + col][ks*32 + quad*8];
      #pragma unroll
      for(int mt=0;mt<2;mt++)
        #pragma unroll
        for(int t=0;t<4;t++)
          acc[mt][t] = __builtin_amdgcn_mfma_f32_16x16x32_bf16(a[mt], b[t], acc[mt][t], 0, 0, 0);
    }
  }
  #pragma unroll
  for(int mt=0;mt<2;mt++){
    #pragma unroll
    for(int r=0;r<4;r++){
      int m = m0 + (wm*2+mt)*16 + quad*4 + r;
      if(m < M){
        #pragma unroll
        for(int t=0;t<4;t++){
          int n = n0 + (wn*4+t)*16 + col;
          float v = acc[mt][t][r];
          if(bias) v += bias[n];
          if(act == 1) v = fmaxf(v, 0.f);
          out[(size_t)m*N + n] = v;
        }
      }
    }
  }
}

// ---------------- row LayerNorm over C=256 (+residual, +act) ----------------
// 4 rows/block (one 64-lane wave per row, 4 els/lane). act: 0 none, 1 relu, 2 sigmoid.
__global__ __launch_bounds__(256) void k_ln256(const float* __restrict__ in, const float* __restrict__ res,
    const float* __restrict__ g, const float* __restrict__ b, float* __restrict__ out, int M, int act)
{
  int row = blockIdx.x*4 + (threadIdx.x >> 6);
  int lane = threadIdx.x & 63;
  if(row >= M) return;
  float4 v = *(const float4*)&in[(size_t)row*C_ + lane*4];
  if(res){
    const float4 rv = *(const float4*)&res[(size_t)row*C_ + lane*4];
    v.x += rv.x; v.y += rv.y; v.z += rv.z; v.w += rv.w;
  }
  float s = v.x + v.y + v.z + v.w;
  float q = v.x*v.x + v.y*v.y + v.z*v.z + v.w*v.w;
  #pragma unroll
  for(int off=32; off; off>>=1){ s += __shfl_xor(s, off, 64); q += __shfl_xor(q, off, 64); }
  float mean = s*(1.f/256.f);
  float rstd = rsqrtf(q*(1.f/256.f) - mean*mean + 1e-5f);
  const float4 gv = *(const float4*)&g[lane*4];
  const float4 bv = *(const float4*)&b[lane*4];
  float o[4] = {(v.x-mean)*rstd*gv.x + bv.x, (v.y-mean)*rstd*gv.y + bv.y,
                (v.z-mean)*rstd*gv.z + bv.z, (v.w-mean)*rstd*gv.w + bv.w};
  #pragma unroll
  for(int j=0;j<4;j++){
    if(act==1) o[j] = fmaxf(o[j], 0.f);
    else if(act==2) o[j] = 1.f/(1.f + __expf(-o[j]));
  }
  float4 ov = {o[0],o[1],o[2],o[3]};
  *(float4*)&out[(size_t)row*C_ + lane*4] = ov;
}

// ---------------- gate = i_in * p_in ----------------
__global__ __launch_bounds__(256) void k_gate(const float* __restrict__ inp, const float* __restrict__ params,
                                              float* __restrict__ gate){
  int i = blockIdx.x*256 + threadIdx.x;
  if(i >= ROWS_*C_) return;
  int c = i & 255, r = i >> 8;
  int np = r / 9;
  gate[i] = inp[(size_t)r*512 + c] * params[(size_t)np*512 + c];
}

// ---------------- block LN helper ----------------
__device__ __forceinline__ void block_stats(float v, float* red, int slot, float& mean, float& rstd){
  float s = v, q = v*v;
  #pragma unroll
  for(int off=32; off; off>>=1){ s += __shfl_xor(s, off, 64); q += __shfl_xor(q, off, 64); }
  int wid = threadIdx.x >> 6;
  if((threadIdx.x & 63) == 0){ red[slot + wid] = s; red[slot + 4 + wid] = q; }
  __syncthreads();
  s = red[slot+0]+red[slot+1]+red[slot+2]+red[slot+3];
  q = red[slot+4]+red[slot+5]+red[slot+6]+red[slot+7];
  mean = s*(1.f/256.f);
  rstd = rsqrtf(q*(1.f/256.f) - mean*mean + 1e-5f);
}

// ---------------- feat = ug * LN(p_out) + ig * LN(i_out) ----------------
__global__ __launch_bounds__(256) void k_combine(const float* __restrict__ params, const float* __restrict__ inp,
  const float* __restrict__ ug, const float* __restrict__ ig,
  const float* __restrict__ nout_g, const float* __restrict__ nout_b,
  const float* __restrict__ inout_g, const float* __restrict__ inout_b,
  float* __restrict__ feat)
{
  __shared__ float red[16];
  int r = blockIdx.x;           // np*9+kk
  int np = r / 9;
  int c = threadIdx.x;
  float pv = params[(size_t)np*512 + 256 + c];
  float mean, rstd;
  block_stats(pv, red, 0, mean, rstd);
  float pn = (pv - mean)*rstd*nout_g[c] + nout_b[c];
  float iv = inp[(size_t)r*512 + 256 + c];
  float mean2, rstd2;
  block_stats(iv, red, 8, mean2, rstd2);
  float iw = (iv - mean2)*rstd2*inout_g[c] + inout_b[c];
  size_t o = (size_t)r*C_ + c;
  feat[o] = ug[o]*pn + ig[o]*iw;
}

// ---------------- attention v2 ----------------
__global__ __launch_bounds__(256) void k_attn2(const float* __restrict__ qkv, float* __restrict__ attnO){
  const int qt = blockIdx.x, h = blockIdx.y, n = blockIdx.z;
  const int q0 = qt*10;
  const int tid = threadIdx.x;
  __shared__ float Qs[10][292];
  __shared__ float KVs[25][292];
  __shared__ float Ss[10][104];
  const float scale = 0.05892556509887896f;   // 1/sqrt(288)
  const size_t base = (size_t)n*P_*6912 + (size_t)h*DH_;
  for(int i=tid; i<10*DH_; i+=256){
    int qi = i/DH_, d = i - qi*DH_;
    Qs[qi][d] = qkv[base + (size_t)(q0+qi)*6912 + d] * scale;
  }
  for(int kt=0; kt<4; kt++){
    int kp0 = kt*25;
    __syncthreads();
    for(int i=tid; i<25*DH_; i+=256){
      int ki = i/DH_, d = i - ki*DH_;
      KVs[ki][d] = qkv[base + (size_t)(kp0+ki)*6912 + E_ + d];
    }
    __syncthreads();
    if(tid < 250){
      int qi = tid/25, ki = tid - qi*25;
      float s = 0.f;
      #pragma unroll 9
      for(int d=0; d<DH_; d+=4){
        const float4 a = *(const float4*)&Qs[qi][d];
        const float4 b = *(const float4*)&KVs[ki][d];
        s += a.x*b.x + a.y*b.y + a.z*b.z + a.w*b.w;
      }
      Ss[qi][kp0+ki] = s;
    }
  }
  __syncthreads();
  {
    int w = tid >> 6, lane = tid & 63;
    for(int r=w; r<10; r+=4){
      float v0 = (lane < 100) ? Ss[r][lane] : -1e30f;
      float v1 = (lane < 36)  ? Ss[r][64+lane] : -1e30f;
      float m = fmaxf(v0, v1);
      #pragma unroll
      for(int off=32; off; off>>=1) m = fmaxf(m, __shfl_xor(m, off, 64));
      float e0 = (lane < 100) ? __expf(v0-m) : 0.f;
      float e1 = (lane < 36)  ? __expf(v1-m) : 0.f;
      float s = e0 + e1;
      #pragma unroll
      for(int off=32; off; off>>=1) s += __shfl_xor(s, off, 64);
      float inv = 1.f/s;
      if(lane < 100) Ss[r][lane] = e0*inv;
      if(lane < 36)  Ss[r][64+lane] = e1*inv;
    }
  }
  float acc[12];
  #pragma unroll
  for(int j=0;j<12;j++) acc[j]=0.f;
  for(int kt=0; kt<4; kt++){
    int kp0 = kt*25;
    __syncthreads();
    for(int i=tid; i<25*DH_; i+=256){
      int ki = i/DH_, d = i - ki*DH_;
      KVs[ki][d] = qkv[base + (size_t)(kp0+ki)*6912 + 2*E_ + d];
    }
    __syncthreads();
    int j = 0;
    for(int i=tid; i<10*DH_; i+=256, j++){
      int qi = i/DH_, d = i - qi*DH_;
      float s = acc[j];
      #pragma unroll
      for(int ki=0; ki<25; ki++) s += Ss[qi][kp0+ki]*KVs[ki][d];
      acc[j] = s;
    }
  }
  {
    int j = 0;
    for(int i=tid; i<10*DH_; i+=256, j++){
      int qi = i/DH_, d = i - qi*DH_;
      attnO[(size_t)(n*P_ + q0 + qi)*E_ + h*DH_ + d] = acc[j];
    }
  }
}

// ---------------- obj1 = LN(obj0 + tproj) over E=2304 ----------------
__global__ __launch_bounds__(256) void k_add_ln2304(const float* __restrict__ obj0, const float* __restrict__ tp,
  const float* __restrict__ g, const float* __restrict__ b, float* __restrict__ out)
{
  __shared__ float red[8];
  int row = blockIdx.x;
  float v[9]; float s=0.f, q=0.f;
  #pragma unroll
  for(int j=0;j<9;j++){
    int e = threadIdx.x + j*256;
    float t = obj0[(size_t)row*E_ + e] + tp[(size_t)row*E_ + e];
    v[j]=t; s+=t; q+=t*t;
  }
  #pragma unroll
  for(int off=32; off; off>>=1){ s += __shfl_xor(s, off, 64); q += __shfl_xor(q, off, 64); }
  int wid = threadIdx.x>>6;
  if((threadIdx.x&63)==0){ red[wid]=s; red[4+wid]=q; }
  __syncthreads();
  s = red[0]+red[1]+red[2]+red[3]; q = red[4]+red[5]+red[6]+red[7];
  float mean = s*(1.f/2304.f);
  float rstd = rsqrtf(q*(1.f/2304.f) - mean*mean + 1e-5f);
  #pragma unroll
  for(int j=0;j<9;j++){
    int e = threadIdx.x + j*256;
    out[(size_t)row*E_ + e] = (v[j]-mean)*rstd*g[e] + b[e];
  }
}

// ---------------- obj_kernels output transpose ----------------
__global__ __launch_bounds__(256) void k_objk(const float* __restrict__ obj2, float* __restrict__ outk){
  int i = blockIdx.x*256 + threadIdx.x;
  if(i >= ROWS_*C_) return;
  int kk = i % 9; int t = i / 9; int c = t & 255; int np = t >> 8;
  outk[i] = obj2[((size_t)np*9 + kk)*C_ + c];
}

// ---------------- dynamic conv via implicit-GEMM bf16 MFMA ----------------
__global__ __launch_bounds__(256) void k_conv_mfma(const float* __restrict__ x, const float* __restrict__ ker,
                                                   float* __restrict__ out){
  const int wt = blockIdx.x, ht = blockIdx.y, z = blockIdx.z;
  const int n = z >> 1, ps = z & 1;
  const int pbase = ps*64;
  const int NT = ps ? 3 : 4;
  const int tid = threadIdx.x;
  const int hi = tid >> 6;
  const int lane = tid & 63;
  const int col = lane & 15, quad = lane >> 4;
  const int w0 = wt*64, h0 = ht*4;

  __shared__ __bf16 xs[6][66][32];
  __shared__ __bf16 ks[9][64][32];

  f32x4 acc[4][4] = {};
  const int npr = NT*16;

  for(int c0=0; c0<C_; c0+=32){
    __syncthreads();
    for(int i=tid; i<1584; i+=256){
      int oct = i / 396;
      int rem = i - oct*396;
      int hy = rem / 66, wx = rem - hy*66;
      int hh = h0 - 1 + hy, ww = w0 - 1 + wx;
      bf16x8 v;
      if(hh >= 0 && hh < H_ && ww >= 0 && ww < W_){
        const float* xp = &x[(((size_t)n*C_ + c0 + oct*8)*H_ + hh)*W_ + ww];
        #pragma unroll
        for(int u=0;u<8;u++) v[u] = (__bf16)xp[(size_t)u*HW_];
      } else {
        #pragma unroll
        for(int u=0;u<8;u++) v[u] = (__bf16)0.f;
      }
      *(bf16x8*)&xs[hy][wx][oct*8] = v;
    }
    for(int i=tid; i<9*npr*4; i+=256){
      int oct = i & 3;
      int t = i >> 2;
      int tap = t / npr, pl = t - tap*npr;
      int p = pbase + pl;
      bf16x8 v;
      if(p < P_){
        const float* kp = &ker[((size_t)(n*P_+p)*9 + tap)*C_ + c0 + oct*8];
        #pragma unroll
        for(int u=0;u<8;u++) v[u] = (__bf16)kp[u];
      } else {
        #pragma unroll
        for(int u=0;u<8;u++) v[u] = (__bf16)0.f;
      }
      *(bf16x8*)&ks[tap][pl][oct*8] = v;
    }
    __syncthreads();
    #pragma unroll
    for(int ky=0; ky<3; ky++){
      #pragma unroll
      for(int kx=0; kx<3; kx++){
        const int tap = ky*3 + kx;
        const int hy = hi + ky;
        bf16x8 b[4];
        #pragma unroll
        for(int t=0;t<4;t++) b[t] = *(const bf16x8*)&xs[hy][t*16 + col + kx][quad*8];
        #pragma unroll
        for(int pt=0; pt<4; pt++){
          if(pt < NT){
            bf16x8 a = *(const bf16x8*)&ks[tap][pt*16 + col][quad*8];
            #pragma unroll
            for(int t=0;t<4;t++)
              acc[pt][t] = __builtin_amdgcn_mfma_f32_16x16x32_bf16(a, b[t], acc[pt][t], 0, 0, 0);
          }
        }
      }
    }
  }
  const int h = h0 + hi;
  #pragma unroll
  for(int pt=0; pt<4; pt++){
    if(pt < NT){
      #pragma unroll
      for(int r=0;r<4;r++){
        int p = pbase + pt*16 + quad*4 + r;
        if(p < P_){
          float* op = &out[((size_t)(n*P_+p)*H_ + h)*W_ + w0 + col];
          #pragma unroll
          for(int t=0;t<4;t++) op[t*16] = acc[pt][t][r];
        }
      }
    }
  }
}

extern "C" void kernel_launch(void* const* d_in, const int* in_sizes, int n_in,
                              void* d_out, int out_size, void* d_ws, size_t ws_size,
                              hipStream_t stream)
{
  (void)in_sizes; (void)n_in; (void)out_size; (void)ws_size;
  const float* x          = (const float*)d_in[0];
  const float* prop       = (const float*)d_in[1];
  const float* mask_pred  = (const float*)d_in[2];
  const float* ku_dyn_w   = (const float*)d_in[3];
  const float* ku_dyn_b   = (const float*)d_in[4];
  const float* ku_in_w    = (const float*)d_in[5];
  const float* ku_in_b    = (const float*)d_in[6];
  const float* ku_ig_w    = (const float*)d_in[7];
  const float* ku_ig_b    = (const float*)d_in[8];
  const float* ku_ug_w    = (const float*)d_in[9];
  const float* ku_ug_b    = (const float*)d_in[10];
  const float* ku_nin_g   = (const float*)d_in[11];
  const float* ku_nin_b   = (const float*)d_in[12];
  const float* ku_nout_g  = (const float*)d_in[13];
  const float* ku_nout_b  = (const float*)d_in[14];
  const float* ku_inin_g  = (const float*)d_in[15];
  const float* ku_inin_b  = (const float*)d_in[16];
  const float* ku_inout_g = (const float*)d_in[17];
  const float* ku_inout_b = (const float*)d_in[18];
  const float* ku_fc_w    = (const float*)d_in[19];
  const float* ku_fc_b    = (const float*)d_in[20];
  const float* ku_fcn_g   = (const float*)d_in[21];
  const float* ku_fcn_b   = (const float*)d_in[22];
  const float* attn_in_w  = (const float*)d_in[23];
  const float* attn_in_b  = (const float*)d_in[24];
  const float* attn_out_w = (const float*)d_in[25];
  const float* attn_out_b = (const float*)d_in[26];
  const float* attn_ln_g  = (const float*)d_in[27];
  const float* attn_ln_b  = (const float*)d_in[28];
  const float* ffn_w1     = (const float*)d_in[29];
  const float* ffn_b1     = (const float*)d_in[30];
  const float* ffn_w2     = (const float*)d_in[31];
  const float* ffn_b2     = (const float*)d_in[32];
  const float* ffn_ln_g   = (const float*)d_in[33];
  const float* ffn_ln_b   = (const float*)d_in[34];
  const float* mask_fc_ws = (const float*)d_in[35];
  const float* mask_fc_ln_g = (const float*)d_in[36];
  const float* mask_fc_ln_b = (const float*)d_in[37];
  const float* fc_mask_w  = (const float*)d_in[38];
  const float* fc_mask_b  = (const float*)d_in[39];

  float* ws = (float*)d_ws;
  float* sig     = ws;
  float* hbuf    = ws;
  float* partial = ws + 4915200;      // dead after k_xfeat2
  float* qkv     = ws + 4915200;
  float* attnO   = ws + 4915200 + 1382400;
  float* tproj   = ws + 4915200 + 1843200;
  float* tmp     = ws + 4915200 + 2304000;  // pre-LN gemm output (1800x256)
  float* xfeat   = ws + 9830400;
  float* params  = xfeat + 51200;
  float* pf      = params + 102400;
  float* inp     = pf + 460800;
  float* gate    = inp + 921600;
  float* ig      = gate + 460800;
  float* ug      = ig + 460800;
  float* feat    = ug + 460800;
  float* obj0    = feat + 460800;
  float* obj1    = obj0 + 460800;
  float* obj2    = obj1 + 460800;
  float* mf1     = obj2 + 460800;
  float* mf2     = mf1 + 460800;
  float* mfF     = mf2 + 460800;

  float* out_masks = (float*)d_out;
  float* out_kern  = out_masks + (size_t)N_*P_*HW_;

  k_softmax<<<192, 256, 0, stream>>>(mask_pred, sig);
  k_permute_pf<<<1800, 256, 0, stream>>>(prop, pf);
  k_xfeat1m<<<dim3(2,XKC_,2), 256, 0, stream>>>(sig, x, partial);
  k_xfeat2<<<200, 256, 0, stream>>>(partial, xfeat);
  k_gemm_mfma<<<dim3(4,4),   256, 0, stream>>>(xfeat, ku_dyn_w, ku_dyn_b, params, 200, 512, 256, 0);
  k_gemm_mfma<<<dim3(4,29),  256, 0, stream>>>(pf, ku_in_w, ku_in_b, inp, 1800, 512, 256, 0);
  k_gate<<<1800, 256, 0, stream>>>(inp, params, gate);
  k_gemm_mfma<<<dim3(2,29),  256, 0, stream>>>(gate, ku_ig_w, ku_ig_b, tmp, 1800, 256, 256, 0);
  k_ln256<<<450, 256, 0, stream>>>(tmp, nullptr, ku_inin_g, ku_inin_b, ig, 1800, 2);
  k_gemm_mfma<<<dim3(2,29),  256, 0, stream>>>(gate, ku_ug_w, ku_ug_b, tmp, 1800, 256, 256, 0);
  k_ln256<<<450, 256, 0, stream>>>(tmp, nullptr, ku_nin_g, ku_nin_b, ug, 1800, 2);
  k_combine<<<1800, 256, 0, stream>>>(params, inp, ug, ig, ku_nout_g, ku_nout_b, ku_inout_g, ku_inout_b, feat);
  k_gemm_mfma<<<dim3(2,29),  256, 0, stream>>>(feat, ku_fc_w, ku_fc_b, tmp, 1800, 256, 256, 0);
  k_ln256<<<450, 256, 0, stream>>>(tmp, nullptr, ku_fcn_g, ku_fcn_b, obj0, 1800, 1);
  k_gemm_mfma<<<dim3(54,4),  256, 0, stream>>>(obj0, attn_in_w, attn_in_b, qkv, 200, 6912, 2304, 0);
  k_attn2<<<dim3(10,8,2), 256, 0, stream>>>(qkv, attnO);
  k_gemm_mfma<<<dim3(18,4),  256, 0, stream>>>(attnO, attn_out_w, attn_out_b, tproj, 200, 2304, 2304, 0);
  k_add_ln2304<<<200, 256, 0, stream>>>(obj0, tproj, attn_ln_g, attn_ln_b, obj1);
  k_gemm_mfma<<<dim3(16,29), 256, 0, stream>>>(obj1, ffn_w1, ffn_b1, hbuf, 1800, 2048, 256, 1);
  k_gemm_mfma<<<dim3(2,29),  256, 0, stream>>>(hbuf, ffn_w2, ffn_b2, tmp, 1800, 256, 2048, 0);
  k_ln256<<<450, 256, 0, stream>>>(tmp, obj1, ffn_ln_g, ffn_ln_b, obj2, 1800, 0);
  k_gemm_mfma<<<dim3(2,29),  256, 0, stream>>>(obj2, mask_fc_ws,          nullptr, tmp, 1800, 256, 256, 0);
  k_ln256<<<450, 256, 0, stream>>>(tmp, nullptr, mask_fc_ln_g,       mask_fc_ln_b,       mf1, 1800, 1);
  k_gemm_mfma<<<dim3(2,29),  256, 0, stream>>>(mf1,  mask_fc_ws + 65536,  nullptr, tmp, 1800, 256, 256, 0);
  k_ln256<<<450, 256, 0, stream>>>(tmp, nullptr, mask_fc_ln_g + 256, mask_fc_ln_b + 256, mf2, 1800, 1);
  k_gemm_mfma<<<dim3(2,29),  256, 0, stream>>>(mf2,  mask_fc_ws + 131072, nullptr, tmp, 1800, 256, 256, 0);
  k_ln256<<<450, 256, 0, stream>>>(tmp, nullptr, mask_fc_ln_g + 512, mask_fc_ln_b + 512, mf1, 1800, 1);
  k_gemm_mfma<<<dim3(2,29),  256, 0, stream>>>(mf1, fc_mask_w, fc_mask_b, mfF, 1800, 256, 256, 0);
  k_objk<<<1800, 256, 0, stream>>>(obj2, out_kern);
  k_conv_mfma<<<dim3(3,32,4), 256, 0, stream>>>(x, mfF, out_masks);
}